// Round 7
// baseline (714.247 us; speedup 1.0000x reference)
//
#include <hip/hip_runtime.h>
#include <hip/hip_bf16.h>
#include <cmath>

// Inputs/outputs float32. Geometry/sampling fp32 (k0/k1/k2). nf + rt chains as
// bf16 MFMA GEMMs (fp32 accum), LN fused into A-staging, bias/lrelu/residual
// in epilogue. Chunked over M with chunk arena sized to stay L3-resident
// (<=64MB): producer->consumer hops hit Infinity Cache, not HBM.
// GEMM grid: N-tiles on x (fast), M-tiles on y -> same-A-tile blocks adjacent.

using bf16 = __hip_bfloat16;
#define DEV __device__ __forceinline__

typedef __attribute__((ext_vector_type(8))) short short8;
typedef __attribute__((ext_vector_type(4))) float f32x4;

DEV float s2f(short s){ unsigned u=((unsigned)(unsigned short)s)<<16; float f; __builtin_memcpy(&f,&u,4); return f; }
DEV short f2s(float f){ bf16 h=__float2bfloat16(f); short r; __builtin_memcpy(&r,&h,2); return r; }

constexpr int NRAY=256, SP=64, SI=32, S=96, KHR=8, CIN=32, C=128, NH=8, DH=16;
constexpr int NT = NRAY*S;           // 24576 tokens
constexpr int MTOT = NT*KHR;         // 196608 rows in the nf chain

// ---- fp32 ws region (element offsets) ----
constexpr size_t OFF_RI=0, OFF_TR=9, OFF_M=16, OFF_TN=272, OFF_TF=528, OFF_RDO=784,
  OFF_TS=1552, OFF_OCCS=26128, OFF_OCCT=50704, OFF_CRD=75280, OFF_XS=149008, F32_CNT=935440;

// ---- bf16 ws region (element offsets from bf16 base) ----
constexpr size_t WT_W0=0, WT_NQKV=8192, WT_NO=57344, WT_NF1=73728, WT_NF2=106496,
  WT_RQKV=139264, WT_RO=188416, WT_RF1=204800, WT_RF2=237568, WT_TOT=270336;
constexpr size_t H2OFF=WT_TOT;                 // h2: NT*128
constexpr size_t CHB=H2OFF+(size_t)NT*128;     // chunk / rt arena base
constexpr size_t RT_TOT=(size_t)NT*512;        // compacted rt arena

struct Corn { int off[8]; float wz, wy, wx; };

DEV void make_corners(float cz, float cy, float cx, Corn& Cn){
  cz=fminf(fmaxf(cz,0.f),31.f); cy=fminf(fmaxf(cy,0.f),31.f); cx=fminf(fmaxf(cx,0.f),31.f);
  int z0=(int)cz, y0=(int)cy, x0=(int)cx;
  int z1=(z0+1<31)?z0+1:31, y1=(y0+1<31)?y0+1:31, x1=(x0+1<31)?x0+1:31;
  Cn.wz=cz-(float)z0; Cn.wy=cy-(float)y0; Cn.wx=cx-(float)x0;
  int zy00=z0*1024+y0*32, zy01=z0*1024+y1*32, zy10=z1*1024+y0*32, zy11=z1*1024+y1*32;
  Cn.off[0]=zy00+x0; Cn.off[1]=zy00+x1;
  Cn.off[2]=zy01+x0; Cn.off[3]=zy01+x1;
  Cn.off[4]=zy10+x0; Cn.off[5]=zy10+x1;
  Cn.off[6]=zy11+x0; Cn.off[7]=zy11+x1;
}

DEV float interp1(const float* __restrict__ vol, const Corn& Cn){
  float v000=vol[Cn.off[0]], v001=vol[Cn.off[1]];
  float v010=vol[Cn.off[2]], v011=vol[Cn.off[3]];
  float v100=vol[Cn.off[4]], v101=vol[Cn.off[5]];
  float v110=vol[Cn.off[6]], v111=vol[Cn.off[7]];
  float wx=Cn.wx, wy=Cn.wy, wz=Cn.wz;
  float c00=v000*(1.f-wx)+v001*wx, c01=v010*(1.f-wx)+v011*wx;
  float c10=v100*(1.f-wx)+v101*wx, c11=v110*(1.f-wx)+v111*wx;
  return (c00*(1.f-wy)+c01*wy)*(1.f-wz) + (c10*(1.f-wy)+c11*wy)*wz;
}

DEV float ray_box(const float* Ri, const float* tr, const float* o3, const float* d3, const float* half){
  float tlo=-INFINITY, thi=INFINITY;
  for(int j=0;j<3;j++){
    float oo=Ri[j*3+0]*o3[0]+Ri[j*3+1]*o3[1]+Ri[j*3+2]*o3[2]+tr[j];
    float dd=Ri[j*3+0]*d3[0]+Ri[j*3+1]*d3[1]+Ri[j*3+2]*d3[2];
    if (fabsf(dd)<1e-9f) dd=1e-9f;
    float inv=1.f/dd;
    float t0=(-half[j]-oo)*inv, t1=(half[j]-oo)*inv;
    tlo=fmaxf(tlo,fminf(t0,t1)); thi=fminf(thi,fmaxf(t0,t1));
  }
  bool valid = thi >= fmaxf(tlo,0.f);
  return valid ? tlo : INFINITY;
}

// ============================= k0: pose inverse + ray-box =============================
__global__ __launch_bounds__(64) void k0_setup(
  const float* __restrict__ rays_o, const float* __restrict__ rays_d,
  const float* __restrict__ pose, const float* __restrict__ dimv,
  float* __restrict__ wsf)
{
  __shared__ float Ri[9], tr[3];
  int tid=threadIdx.x; int ray=blockIdx.x*64+tid;
  if(tid==0){
    float P[16];
    for(int j=0;j<16;j++) P[j]=pose[j];
    float a00=P[0],a01=P[1],a02=P[2],a10=P[4],a11=P[5],a12=P[6],a20=P[8],a21=P[9],a22=P[10];
    float c00=a11*a22-a12*a21, c01=a12*a20-a10*a22, c02=a10*a21-a11*a20;
    float det=a00*c00+a01*c01+a02*c02;
    float id=1.f/det;
    Ri[0]=c00*id; Ri[1]=(a02*a21-a01*a22)*id; Ri[2]=(a01*a12-a02*a11)*id;
    Ri[3]=c01*id; Ri[4]=(a00*a22-a02*a20)*id; Ri[5]=(a02*a10-a00*a12)*id;
    Ri[6]=c02*id; Ri[7]=(a01*a20-a00*a21)*id; Ri[8]=(a00*a11-a01*a10)*id;
    float t0=P[3],t1=P[7],t2=P[11];
    tr[0]=-(Ri[0]*t0+Ri[1]*t1+Ri[2]*t2);
    tr[1]=-(Ri[3]*t0+Ri[4]*t1+Ri[5]*t2);
    tr[2]=-(Ri[6]*t0+Ri[7]*t1+Ri[8]*t2);
    if(blockIdx.x==0){
      for(int j=0;j<9;j++) wsf[OFF_RI+j]=Ri[j];
      for(int j=0;j<3;j++) wsf[OFF_TR+j]=tr[j];
    }
  }
  __syncthreads();
  float o3[3],d3[3],dim[3],half[3];
  for(int j=0;j<3;j++){ o3[j]=rays_o[ray*3+j]; d3[j]=rays_d[ray*3+j];
                        dim[j]=dimv[j]; half[j]=0.5f*dim[j]; }
  float tnear=ray_box(Ri,tr,o3,d3,half);
  float tmax=tnear+10.f*(fabsf(dim[0])+fabsf(dim[1])+fabsf(dim[2]));
  float pm[3]={o3[0]+tmax*d3[0], o3[1]+tmax*d3[1], o3[2]+tmax*d3[2]};
  float nd[3]={-d3[0],-d3[1],-d3[2]};
  float tfar=tmax-ray_box(Ri,tr,pm,nd,half);
  bool mm = isfinite(tnear)&&isfinite(tfar)&&(tfar>tnear);
  wsf[OFF_M+ray]=mm?1.f:0.f;
  wsf[OFF_TN+ray]=mm?tnear:0.f;
  wsf[OFF_TF+ray]=mm?tfar:1.f;
  for(int j=0;j<3;j++)
    wsf[OFF_RDO+(size_t)ray*3+j]=Ri[j*3+0]*d3[0]+Ri[j*3+1]*d3[1]+Ri[j*3+2]*d3[2];
}

// ============================= k1: sampling + interp + stable sort =============================
__global__ __launch_bounds__(128) void k1_sample(
  const float* __restrict__ rays_o, const float* __restrict__ rays_d, const float* __restrict__ dimv,
  const float* __restrict__ voxel, const float* __restrict__ fvol,
  const float* __restrict__ u_p, const float* __restrict__ u_cat, const float* __restrict__ u_lam,
  float* __restrict__ wsf)
{
  int i=blockIdx.x, tid=threadIdx.x;
  __shared__ float Ri[9], tr[3], dim[3], o3[3], d3[3];
  __shared__ float t_all[S], occ_all[S], crd_sh[S][3];
  __shared__ int   coff[S][8];
  __shared__ float cww[S][3];
  __shared__ float cdf[SP];
  __shared__ float totv;
  __shared__ int   rnk[S];
  if(tid<9) Ri[tid]=wsf[OFF_RI+tid];
  if(tid<3){ tr[tid]=wsf[OFF_TR+tid]; dim[tid]=dimv[tid];
             o3[tid]=rays_o[i*3+tid]; d3[tid]=rays_d[i*3+tid]; }
  __syncthreads();
  float tn=wsf[OFF_TN+i], tf=wsf[OFF_TF+i];

  auto do_sample=[&](int s, float t){
    float px=o3[0]+t*d3[0], py=o3[1]+t*d3[1], pz=o3[2]+t*d3[2];
    float q0=Ri[0]*px+Ri[1]*py+Ri[2]*pz+tr[0];
    float q1=Ri[3]*px+Ri[4]*py+Ri[5]*pz+tr[1];
    float q2=Ri[6]*px+Ri[7]*py+Ri[8]*pz+tr[2];
    float cz=(0.5f+q2/dim[2])*31.f;
    float cy=(0.5f+q1/dim[1])*31.f;
    float cx=(0.5f+q0/dim[0])*31.f;
    crd_sh[s][0]=cz; crd_sh[s][1]=cy; crd_sh[s][2]=cx;
    Corn Cn; make_corners(cz,cy,cx,Cn);
    for(int q=0;q<8;q++) coff[s][q]=Cn.off[q];
    cww[s][0]=Cn.wz; cww[s][1]=Cn.wy; cww[s][2]=Cn.wx;
    occ_all[s]=interp1(voxel,Cn);
    t_all[s]=t;
  };

  if(tid<SP){
    float u=u_p[i*SP+tid];
    float t=tn+(tf-tn)*((float)tid+u)*(1.f/64.f);
    do_sample(tid,t);
  }
  __syncthreads();
  if(tid==0){
    float c=0;
    for(int j=0;j<SP-1;j++){ float pr=occ_all[j]+occ_all[j+1]; pr=fmaxf(pr,1e-12f); c+=pr; cdf[j]=c; }
    totv=c;
  }
  __syncthreads();
  if(tid<SP-1) cdf[tid]=cdf[tid]/totv;
  __syncthreads();
  if(tid<SI){
    float u=u_cat[i*SI+tid];
    int cnt=0;
    for(int j=0;j<SP-1;j++) cnt += (u>=cdf[j])?1:0;
    int ind=(cnt<SP-2)?cnt:(SP-2);
    float lam=u_lam[i*SI+tid];
    float tfine=lam*t_all[ind]+(1.f-lam)*t_all[ind+1];
    do_sample(SP+tid,tfine);
  }
  __syncthreads();
  if(tid<S){  // stable counting-rank sort (== stable argsort)
    float ts=t_all[tid]; int r=0;
    for(int j=0;j<S;j++){ float tj=t_all[j]; r += (tj<ts || (tj==ts && j<tid)) ? 1:0; }
    rnk[tid]=r;
    size_t base=(size_t)i*S+r;
    wsf[OFF_TS+base]=ts;
    wsf[OFF_OCCS+base]=occ_all[tid];
    wsf[OFF_CRD+base*3+0]=crd_sh[tid][0];
    wsf[OFF_CRD+base*3+1]=crd_sh[tid][1];
    wsf[OFF_CRD+base*3+2]=crd_sh[tid][2];
  }
  __syncthreads();
  for(int idx=tid; idx<S*CIN; idx+=128){
    int s=idx>>5, c=idx&31;
    float wz=cww[s][0], wy=cww[s][1], wx=cww[s][2];
    const float* vc=fvol+(size_t)c*32768;
    float v000=vc[coff[s][0]], v001=vc[coff[s][1]];
    float v010=vc[coff[s][2]], v011=vc[coff[s][3]];
    float v100=vc[coff[s][4]], v101=vc[coff[s][5]];
    float v110=vc[coff[s][6]], v111=vc[coff[s][7]];
    float c00=v000*(1.f-wx)+v001*wx, c01=v010*(1.f-wx)+v011*wx;
    float c10=v100*(1.f-wx)+v101*wx, c11=v110*(1.f-wx)+v111*wx;
    float val=(c00*(1.f-wy)+c01*wy)*(1.f-wz)+(c10*(1.f-wy)+c11*wy)*wz;
    wsf[OFF_XS+((size_t)i*S+rnk[s])*CIN+c]=val;
  }
}

// ============================= k2: sigma MLP, alpha, outputs 0..2 =============================
__global__ __launch_bounds__(128) void k2_sigma(
  const float* __restrict__ dW1, const float* __restrict__ db1,
  const float* __restrict__ dW2, const float* __restrict__ db2,
  float* __restrict__ wsf, float* __restrict__ out)
{
  int t=blockIdx.x, tid=threadIdx.x, i=t/S;
  __shared__ float xx[33];
  __shared__ float part[2];
  if(tid<32) xx[tid]=wsf[OFF_XS+(size_t)t*32+tid];
  if(tid==32) xx[32]=wsf[OFF_OCCS+t];
  __syncthreads();
  float acc=db1[tid];
  for(int k=0;k<33;k++) acc=fmaf(xx[k], dW1[k*C+tid], acc);
  acc = acc>=0.f?acc:0.01f*acc;
  float g = acc*dW2[tid];
  for(int off=32;off;off>>=1) g+=__shfl_down(g,off,64);
  if((tid&63)==0) part[tid>>6]=g;
  __syncthreads();
  if(tid==0){
    float z=part[0]+part[1]+db2[0];
    float sg=1.f/(1.f+expf(-z));
    float occ=xx[32];
    float occt=occ<0.7f?0.f:occ;
    float alpha=occt*sg;
    float m=wsf[OFF_M+i];
    float ts=wsf[OFF_TS+t];
    out[t]      =m!=0.f?ts:0.f;
    out[NT+t]   =m!=0.f?alpha:0.f;
    out[2*NT+t] =m!=0.f?occt:0.f;
    wsf[OFF_OCCT+t]=occt;
  }
}

// ============================= weight prep: fp32 KxN -> bf16 N x Kpad (B^T) =============================
__global__ __launch_bounds__(256) void k_wprep(
  const float* __restrict__ w0, const float* __restrict__ nqkv, const float* __restrict__ no_,
  const float* __restrict__ nf1, const float* __restrict__ nf2,
  const float* __restrict__ rqkv, const float* __restrict__ ro_,
  const float* __restrict__ rf1, const float* __restrict__ rf2,
  short* __restrict__ WT)
{
  int gid = blockIdx.x*256+threadIdx.x;
  if(gid>=(int)WT_TOT) return;
  const float* src; int K,N,Kp; int base;
  if(gid<8192){src=w0;K=42;N=128;Kp=64;base=0;}
  else if(gid<57344){src=nqkv;K=128;N=384;Kp=128;base=8192;}
  else if(gid<73728){src=no_;K=128;N=128;Kp=128;base=57344;}
  else if(gid<106496){src=nf1;K=128;N=256;Kp=128;base=73728;}
  else if(gid<139264){src=nf2;K=256;N=128;Kp=256;base=106496;}
  else if(gid<188416){src=rqkv;K=128;N=384;Kp=128;base=139264;}
  else if(gid<204800){src=ro_;K=128;N=128;Kp=128;base=188416;}
  else if(gid<237568){src=rf1;K=128;N=256;Kp=128;base=204800;}
  else {src=rf2;K=256;N=128;Kp=256;base=237568;}
  int local=gid-base; int n=local/Kp, k=local%Kp;
  WT[gid] = (k<K)? f2s(src[(size_t)k*N+n]) : (short)0;
}

// ============================= xx2 builder: X2 (rows x 64 bf16, cols42..63=0) =============================
__global__ __launch_bounds__(64) void k_build(
  const float* __restrict__ fvhr, const float* __restrict__ wsf,
  short* __restrict__ X2, int tok0)
{
  int tloc=blockIdx.x, tid=threadIdx.x;
  int t=tok0+tloc, i=t/S;
  __shared__ float hr[KHR][6];
  __shared__ float xf[32];
  __shared__ float RiS[9];
  __shared__ float geo[4];
  __shared__ float crd[3];
  if(tid<9) RiS[tid]=wsf[OFF_RI+tid];
  if(tid>=16&&tid<19) crd[tid-16]=wsf[OFF_CRD+(size_t)t*3+(tid-16)];
  if(tid>=32) xf[tid-32]=wsf[OFF_XS+(size_t)t*32+(tid-32)];
  if(tid==9) geo[0]=wsf[OFF_OCCT+t];
  if(tid>=12&&tid<15) geo[1+(tid-12)]=wsf[OFF_RDO+(size_t)i*3+(tid-12)];
  __syncthreads();
  if(tid<48){
    int k=tid/6, ch=tid%6;
    Corn Cn; make_corners(crd[0],crd[1],crd[2],Cn);
    hr[k][ch]=interp1(fvhr+(size_t)(k*6+ch)*32768, Cn);
  }
  __syncthreads();
  for(int idx=tid; idx<512; idx+=64){
    int k=idx>>6, j=idx&63; float v;
    if(j<32) v=xf[j];
    else if(j<35) v=hr[k][j-32];
    else if(j<38){int r=j-35; v=hr[k][3]*RiS[r*3+0]+hr[k][4]*RiS[r*3+1]+hr[k][5]*RiS[r*3+2];}
    else if(j<41) v=geo[1+(j-38)];
    else if(j==41) v=geo[0];
    else v=0.f;
    X2[(size_t)(tloc*8+k)*64 + j]=f2s(v);
  }
}

// ============================= MFMA GEMM: C = [LN?](A) @ Bt^T + bias [+lrelu] [+resid] =============================
// Grid: x = N-tiles (fast-varying -> same-A-tile blocks adjacent), y = M-tiles.
template<int K, bool LNA, bool ACT, bool RESID>
__global__ __launch_bounds__(256) void gemm_ln(
  const short* __restrict__ A, const short* __restrict__ Bt,
  const float* __restrict__ bias, const short* __restrict__ Rres,
  short* __restrict__ Cg, int N)
{
  static_assert(!LNA || K==128, "LNA requires K==128");
  constexpr int KSA = (K<128)?K:128;
  constexpr int NSA = K/KSA;
  constexpr int LDA = KSA+8;
  constexpr int LDB = 64+8;
  __shared__ short Al[128*LDA];
  __shared__ short Bl[128*LDB];
  const int tid=threadIdx.x;
  const int bm=blockIdx.y*128, bn=blockIdx.x*128;
  const int lane=tid&63, wave=tid>>6;
  const int wm=(wave>>1)*64, wn=(wave&1)*64;
  const int quad=lane>>4, m16=lane&15;
  f32x4 acc[4][4];
  for(int a=0;a<4;a++) for(int b=0;b<4;b++) acc[a][b]=(f32x4){0.f,0.f,0.f,0.f};

  for(int sa=0; sa<NSA; ++sa){
    if(sa>0) __syncthreads();
    constexpr int CH8=KSA/8;
    for(int it=0; it<(128*CH8)/256; ++it){
      int li=it*256+tid; int row=li/CH8, kc=li%CH8;
      short8 v = *(const short8*)(A + (size_t)(bm+row)*K + sa*KSA + kc*8);
      if constexpr(LNA){
        float f[8]; float ls=0.f,lq=0.f;
        for(int e=0;e<8;e++){ f[e]=s2f(v[e]); ls+=f[e]; lq+=f[e]*f[e]; }
        for(int off=8;off;off>>=1){ ls+=__shfl_xor(ls,off,16); lq+=__shfl_xor(lq,off,16); }
        float mu=ls*(1.f/128.f);
        float var=lq*(1.f/128.f)-mu*mu;
        float rs=rsqrtf(var+1e-5f);
        for(int e=0;e<8;e++) v[e]=f2s((f[e]-mu)*rs);
      }
      *(short8*)&Al[row*LDA+kc*8]=v;
    }
    __syncthreads();
    for(int sb=0; sb<KSA/64; ++sb){
      if(sb>0) __syncthreads();
      for(int it=0; it<4; ++it){
        int li=it*256+tid; int row=li>>3, kc=li&7;
        *(short8*)&Bl[row*LDB+kc*8] =
          *(const short8*)(Bt + (size_t)(bn+row)*K + sa*KSA + sb*64 + kc*8);
      }
      __syncthreads();
      for(int kk=0; kk<64; kk+=32){
        int ka = sb*64+kk;
        short8 af[4], bfv[4];
        for(int im=0; im<4; im++)
          af[im] = *(const short8*)&Al[(wm+im*16+m16)*LDA + ka + quad*8];
        for(int in=0; in<4; in++)
          bfv[in] = *(const short8*)&Bl[(wn+in*16+m16)*LDB + kk + quad*8];
        for(int im=0;im<4;im++)
          for(int in=0;in<4;in++)
            acc[im][in] = __builtin_amdgcn_mfma_f32_16x16x32_bf16(af[im], bfv[in], acc[im][in], 0,0,0);
      }
    }
  }
  // epilogue
  for(int in=0;in<4;in++){
    int col = bn + wn + in*16 + m16;
    float bv = bias[col];
    for(int im=0;im<4;im++){
      for(int r=0;r<4;r++){
        int grow = bm + wm + im*16 + quad*4 + r;
        float v = acc[im][in][r] + bv;
        if constexpr(ACT) v = v>=0.f? v : 0.01f*v;
        if constexpr(RESID) v += s2f(Rres[(size_t)grow*N + col]);
        Cg[(size_t)grow*N + col] = f2s(v);
      }
    }
  }
}

// ============================= nf attention: K=8 tokens (padded LDS) =============================
__global__ __launch_bounds__(256) void nf_attn(const short* __restrict__ qkv, short* __restrict__ att){
  constexpr int QLD=392;  // 196 words; 196%32=4 -> conflict-free spread
  __shared__ short Qs[4*8*QLD];
  int t0=blockIdx.x*4, tid=threadIdx.x;
  for(int li=tid; li<1536; li+=256){
    int e=li*8;
    int tok=e/3072, rem=e-tok*3072;
    int j=rem/384, k=rem-j*384;
    *(short8*)&Qs[(tok*8+j)*QLD + k] = *(const short8*)(qkv + (size_t)t0*3072 + e);
  }
  __syncthreads();
  int lt=tid>>6, lane=tid&63;
  int h=lane>>3, q=lane&7;
  const short* base = &Qs[(lt*8)*QLD + h*16];
  float qv[16];
  for(int d=0;d<16;d++) qv[d]=s2f(base[q*QLD+d]);
  float sc[8]; float mx=-INFINITY;
  for(int j=0;j<8;j++){
    float a=0;
    for(int d=0;d<16;d++) a+=qv[d]*s2f(base[j*QLD+128+d]);
    a*=0.25f; sc[j]=a; mx=fmaxf(mx,a);
  }
  float se=0;
  for(int j=0;j<8;j++){ sc[j]=expf(sc[j]-mx); se+=sc[j]; }
  float inv=1.f/se;
  float o[16];
  for(int d=0;d<16;d++) o[d]=0.f;
  for(int j=0;j<8;j++){
    float p=sc[j];
    for(int d=0;d<16;d++) o[d]+=p*s2f(base[j*QLD+256+d]);
  }
  short* ob = att + (size_t)(t0*8 + lt*8 + q)*128 + h*16;
  for(int d=0;d<16;d++) ob[d]=f2s(o[d]*inv);
}

// ============================= rt attention: 4 heads/block, 3 q-rows/thread =============================
__global__ __launch_bounds__(128) void rt_attn(const short* __restrict__ qkvb, short* __restrict__ attout){
  int b=blockIdx.x; int i=b&255, h0=(b>>8)*4; int tid=threadIdx.x;
  __shared__ float kh[96][64], vh[96][64];   // 49152 B
  for(int idx=tid; idx<1536; idx+=128){
    int kv = idx>=768; int l = idx - (kv<<9) - (kv<<8);  // idx - kv*768
    int j = l>>3, c = l&7;
    size_t base = ((size_t)(i*96+j))*384 + h0*16 + (kv?256:128) + c*8;
    short8 x = *(const short8*)(qkvb+base);
    float* dst = kv? &vh[j][c*8] : &kh[j][c*8];
    for(int e=0;e<8;e++) dst[e]=s2f(x[e]);
  }
  __syncthreads();
  int hh=tid>>5, lq=tid&31, h=h0+hh, r0=lq*3;
  float q[3][16];
  for(int rr=0;rr<3;rr++){
    size_t qb=((size_t)(i*96+r0+rr))*384 + h*16;
    short8 a=*(const short8*)(qkvb+qb), bq=*(const short8*)(qkvb+qb+8);
    for(int e=0;e<8;e++){ q[rr][e]=s2f(a[e]); q[rr][8+e]=s2f(bq[e]); }
  }
  float acc[3][16]; float se0=0.f,se1=0.f,se2=0.f;
  for(int rr=0;rr<3;rr++) for(int d=0;d<16;d++) acc[rr][d]=0.f;
  const float* kbase=&kh[0][hh*16];
  const float* vbase=&vh[0][hh*16];
  for(int j=0;j<96;j++){
    const float* kj = kbase + j*64;
    float s0=0.f,s1=0.f,s2=0.f;
    for(int d=0;d<16;d++){ float kv_=kj[d];
      s0=fmaf(q[0][d],kv_,s0); s1=fmaf(q[1][d],kv_,s1); s2=fmaf(q[2][d],kv_,s2); }
    float p0=expf(s0*0.25f), p1=expf(s1*0.25f), p2=expf(s2*0.25f);
    se0+=p0; se1+=p1; se2+=p2;
    const float* vj = vbase + j*64;
    for(int d=0;d<16;d++){ float vv=vj[d];
      acc[0][d]=fmaf(p0,vv,acc[0][d]); acc[1][d]=fmaf(p1,vv,acc[1][d]); acc[2][d]=fmaf(p2,vv,acc[2][d]); }
  }
  float inv[3]={1.f/se0, 1.f/se1, 1.f/se2};
  for(int rr=0;rr<3;rr++){
    short8 o0,o1;
    for(int e=0;e<8;e++){ o0[e]=f2s(acc[rr][e]*inv[rr]); o1[e]=f2s(acc[rr][8+e]*inv[rr]); }
    size_t ob=((size_t)(i*96+r0+rr))*128 + h*16;
    *(short8*)(attout+ob)=o0;
    *(short8*)(attout+ob+8)=o1;
  }
}

// ============================= radiance head =============================
__global__ __launch_bounds__(256) void k_rad(
  const short* __restrict__ h3, const float* __restrict__ fW, const float* __restrict__ fb,
  const float* __restrict__ wsf, float* __restrict__ out)
{
  int t=blockIdx.x*256+threadIdx.x;
  if(t>=NT) return;
  int i=t/S;
  float a0=fb[0], a1=fb[1], a2=fb[2];
  for(int c=0;c<C;c++){
    float hv=s2f(h3[(size_t)t*C+c]);
    a0=fmaf(hv,fW[c*3+0],a0);
    a1=fmaf(hv,fW[c*3+1],a1);
    a2=fmaf(hv,fW[c*3+2],a2);
  }
  float m=wsf[OFF_M+i];
  float r0=1.f/(1.f+expf(-a0)), r1=1.f/(1.f+expf(-a1)), r2=1.f/(1.f+expf(-a2));
  size_t ob=3*(size_t)NT+(size_t)t*3;
  out[ob+0]=m!=0.f?r0:0.f;
  out[ob+1]=m!=0.f?r1:0.f;
  out[ob+2]=m!=0.f?r2:0.f;
}

// ============================= mean over KHR=8 -> h2 =============================
__global__ __launch_bounds__(256) void k_mean(const short* __restrict__ x2o, short* __restrict__ h2){
  int bt = blockIdx.x*2 + (threadIdx.x>>7);
  int c = threadIdx.x&127;
  float s=0;
  for(int k=0;k<8;k++) s += s2f(x2o[(size_t)(bt*8+k)*128 + c]);
  h2[(size_t)bt*128+c] = f2s(s*0.125f);
}

extern "C" void kernel_launch(void* const* d_in, const int* in_sizes, int n_in,
                              void* d_out, int out_size, void* d_ws, size_t ws_size,
                              hipStream_t stream) {
  (void)in_sizes; (void)n_in; (void)out_size;
  const float* rays_o =(const float*)d_in[0];
  const float* rays_d =(const float*)d_in[1];
  const float* pose   =(const float*)d_in[2];
  const float* dimv   =(const float*)d_in[3];
  const float* voxel  =(const float*)d_in[4];
  const float* fvol   =(const float*)d_in[5];
  const float* fvhr   =(const float*)d_in[6];
  const float* u_p    =(const float*)d_in[7];
  const float* u_cat  =(const float*)d_in[8];
  const float* u_lam  =(const float*)d_in[9];
  const float* dW1    =(const float*)d_in[10];
  const float* db1    =(const float*)d_in[11];
  const float* dW2    =(const float*)d_in[12];
  const float* db2    =(const float*)d_in[13];
  const float* rW0    =(const float*)d_in[14];
  const float* rb0    =(const float*)d_in[15];
  const float* nf_qkv =(const float*)d_in[16];
  const float* nf_qkvb=(const float*)d_in[17];
  const float* nf_o   =(const float*)d_in[18];
  const float* nf_ob  =(const float*)d_in[19];
  const float* nf_f1  =(const float*)d_in[20];
  const float* nf_f1b =(const float*)d_in[21];
  const float* nf_f2  =(const float*)d_in[22];
  const float* nf_f2b =(const float*)d_in[23];
  const float* rt_qkv =(const float*)d_in[24];
  const float* rt_qkvb=(const float*)d_in[25];
  const float* rt_o   =(const float*)d_in[26];
  const float* rt_ob  =(const float*)d_in[27];
  const float* rt_f1  =(const float*)d_in[28];
  const float* rt_f1b =(const float*)d_in[29];
  const float* rt_f2  =(const float*)d_in[30];
  const float* rt_f2b =(const float*)d_in[31];
  const float* fW     =(const float*)d_in[32];
  const float* fb     =(const float*)d_in[33];

  float* wsf=(float*)d_ws;
  short* wsb=(short*)((char*)d_ws + F32_CNT*4);
  float* out=(float*)d_out;

  // Chunking: arena must stay L3-resident. Target arena <= 64 MB -> nch>=4.
  // Then (rarely) bump further if ws_size demands.
  int nch=1;
  while(nch<8 && ((size_t)MTOT/nch)*640ULL*2ULL > (64ULL<<20)) nch<<=1;
  for(; nch<8; nch<<=1){
    size_t mc_=(size_t)MTOT/nch;
    size_t region=mc_*640ULL; if(region<RT_TOT) region=RT_TOT;
    size_t need=F32_CNT*4 + 2ULL*(CHB + region);
    if(need <= ws_size) break;
  }
  const size_t mc = (size_t)MTOT/nch;
  const int Tc = (int)(mc/8);

  short* WT  = wsb;
  short* H2  = wsb + H2OFF;
  short* arena = wsb + CHB;
  // nf chunk overlays: h0[0,128) qkv[128,512) att/f2out[512,640) x2[512,576)
  // x1[128,256) f1[256,512)
  short* o_h0 = arena;
  short* o_qkv= arena + (size_t)128*mc;
  short* o_x1 = arena + (size_t)128*mc;
  short* o_f1 = arena + (size_t)256*mc;
  short* o_att= arena + (size_t)512*mc;
  short* o_x2 = arena + (size_t)512*mc;
  short* o_f2 = arena + (size_t)512*mc;
  // rt overlays: qkv[0,384) att/h3[384,512) x[0,128) f1[128,384)
  short* r_qkv= arena;
  short* r_att= arena + (size_t)384*NT;
  short* r_x  = arena;
  short* r_f1 = arena + (size_t)128*NT;
  short* r_h3 = arena + (size_t)384*NT;

  k0_setup<<<NRAY/64,64,0,stream>>>(rays_o,rays_d,pose,dimv,wsf);
  k1_sample<<<NRAY,128,0,stream>>>(rays_o,rays_d,dimv,voxel,fvol,u_p,u_cat,u_lam,wsf);
  k2_sigma<<<NT,128,0,stream>>>(dW1,db1,dW2,db2,wsf,out);
  k_wprep<<<(int)((WT_TOT+255)/256),256,0,stream>>>(rW0,nf_qkv,nf_o,nf_f1,nf_f2,rt_qkv,rt_o,rt_f1,rt_f2,WT);

  const int mt=(int)(mc/128);
  for(int ch=0; ch<nch; ++ch){
    int tok0 = ch*Tc;
    k_build<<<Tc,64,0,stream>>>(fvhr, wsf, o_x2, tok0);
    gemm_ln< 64,false,false,false><<<dim3(1,mt),256,0,stream>>>(o_x2, WT+WT_W0,  rb0,     nullptr, o_h0, 128);
    gemm_ln<128,true ,false,false><<<dim3(3,mt),256,0,stream>>>(o_h0, WT+WT_NQKV,nf_qkvb, nullptr, o_qkv,384);
    nf_attn<<<Tc/4,256,0,stream>>>(o_qkv, o_att);
    gemm_ln<128,false,false,true ><<<dim3(1,mt),256,0,stream>>>(o_att,WT+WT_NO,  nf_ob,   o_h0,    o_x1, 128);
    gemm_ln<128,true ,true ,false><<<dim3(2,mt),256,0,stream>>>(o_x1, WT+WT_NF1, nf_f1b,  nullptr, o_f1, 256);
    gemm_ln<256,false,false,true ><<<dim3(1,mt),256,0,stream>>>(o_f1, WT+WT_NF2, nf_f2b,  o_x1,    o_f2, 128);
    k_mean<<<Tc/2,256,0,stream>>>(o_f2, H2 + (size_t)tok0*128);
  }

  gemm_ln<128,true ,false,false><<<dim3(3,NT/128),256,0,stream>>>(H2,   WT+WT_RQKV,rt_qkvb, nullptr, r_qkv,384);
  rt_attn<<<NRAY*2,128,0,stream>>>(r_qkv, r_att);
  gemm_ln<128,false,false,true ><<<dim3(1,NT/128),256,0,stream>>>(r_att,WT+WT_RO,  rt_ob,   H2,      r_x,  128);
  gemm_ln<128,true ,true ,false><<<dim3(2,NT/128),256,0,stream>>>(r_x,  WT+WT_RF1, rt_f1b,  nullptr, r_f1, 256);
  gemm_ln<256,false,false,true ><<<dim3(1,NT/128),256,0,stream>>>(r_f1, WT+WT_RF2, rt_f2b,  r_x,     r_h3, 128);
  k_rad<<<NT/256,256,0,stream>>>(r_h3, fW, fb, wsf, out);
}

// Round 8
// 624.136 us; speedup vs baseline: 1.1444x; 1.1444x over previous
//
#include <hip/hip_runtime.h>
#include <hip/hip_bf16.h>
#include <cmath>

// Inputs/outputs float32. Geometry/sampling fp32 (k0/k1/k2). nf + rt chains as
// bf16 MFMA GEMMs (fp32 accum), LN fused into A-staging, bias/lrelu/residual
// in epilogue. Chunked over M: arena capped at 160MB -> nch=2 (126MB arena is
// L3-resident, grids stay large enough to fill 256 CUs; nch=4 starved the
// grid, nch=1 thrashed L3).
// GEMM grid: N-tiles on x (fast), M-tiles on y -> same-A-tile blocks adjacent.

using bf16 = __hip_bfloat16;
#define DEV __device__ __forceinline__

typedef __attribute__((ext_vector_type(8))) short short8;
typedef __attribute__((ext_vector_type(4))) float f32x4;

DEV float s2f(short s){ unsigned u=((unsigned)(unsigned short)s)<<16; float f; __builtin_memcpy(&f,&u,4); return f; }
DEV short f2s(float f){ bf16 h=__float2bfloat16(f); short r; __builtin_memcpy(&r,&h,2); return r; }

constexpr int NRAY=256, SP=64, SI=32, S=96, KHR=8, CIN=32, C=128, NH=8, DH=16;
constexpr int NT = NRAY*S;           // 24576 tokens
constexpr int MTOT = NT*KHR;         // 196608 rows in the nf chain

// ---- fp32 ws region (element offsets) ----
constexpr size_t OFF_RI=0, OFF_TR=9, OFF_M=16, OFF_TN=272, OFF_TF=528, OFF_RDO=784,
  OFF_TS=1552, OFF_OCCS=26128, OFF_OCCT=50704, OFF_CRD=75280, OFF_XS=149008, F32_CNT=935440;

// ---- bf16 ws region (element offsets from bf16 base) ----
constexpr size_t WT_W0=0, WT_NQKV=8192, WT_NO=57344, WT_NF1=73728, WT_NF2=106496,
  WT_RQKV=139264, WT_RO=188416, WT_RF1=204800, WT_RF2=237568, WT_TOT=270336;
constexpr size_t H2OFF=WT_TOT;                 // h2: NT*128
constexpr size_t CHB=H2OFF+(size_t)NT*128;     // chunk / rt arena base
constexpr size_t RT_TOT=(size_t)NT*512;        // compacted rt arena

struct Corn { int off[8]; float wz, wy, wx; };

DEV void make_corners(float cz, float cy, float cx, Corn& Cn){
  cz=fminf(fmaxf(cz,0.f),31.f); cy=fminf(fmaxf(cy,0.f),31.f); cx=fminf(fmaxf(cx,0.f),31.f);
  int z0=(int)cz, y0=(int)cy, x0=(int)cx;
  int z1=(z0+1<31)?z0+1:31, y1=(y0+1<31)?y0+1:31, x1=(x0+1<31)?x0+1:31;
  Cn.wz=cz-(float)z0; Cn.wy=cy-(float)y0; Cn.wx=cx-(float)x0;
  int zy00=z0*1024+y0*32, zy01=z0*1024+y1*32, zy10=z1*1024+y0*32, zy11=z1*1024+y1*32;
  Cn.off[0]=zy00+x0; Cn.off[1]=zy00+x1;
  Cn.off[2]=zy01+x0; Cn.off[3]=zy01+x1;
  Cn.off[4]=zy10+x0; Cn.off[5]=zy10+x1;
  Cn.off[6]=zy11+x0; Cn.off[7]=zy11+x1;
}

DEV float interp1(const float* __restrict__ vol, const Corn& Cn){
  float v000=vol[Cn.off[0]], v001=vol[Cn.off[1]];
  float v010=vol[Cn.off[2]], v011=vol[Cn.off[3]];
  float v100=vol[Cn.off[4]], v101=vol[Cn.off[5]];
  float v110=vol[Cn.off[6]], v111=vol[Cn.off[7]];
  float wx=Cn.wx, wy=Cn.wy, wz=Cn.wz;
  float c00=v000*(1.f-wx)+v001*wx, c01=v010*(1.f-wx)+v011*wx;
  float c10=v100*(1.f-wx)+v101*wx, c11=v110*(1.f-wx)+v111*wx;
  return (c00*(1.f-wy)+c01*wy)*(1.f-wz) + (c10*(1.f-wy)+c11*wy)*wz;
}

DEV float ray_box(const float* Ri, const float* tr, const float* o3, const float* d3, const float* half){
  float tlo=-INFINITY, thi=INFINITY;
  for(int j=0;j<3;j++){
    float oo=Ri[j*3+0]*o3[0]+Ri[j*3+1]*o3[1]+Ri[j*3+2]*o3[2]+tr[j];
    float dd=Ri[j*3+0]*d3[0]+Ri[j*3+1]*d3[1]+Ri[j*3+2]*d3[2];
    if (fabsf(dd)<1e-9f) dd=1e-9f;
    float inv=1.f/dd;
    float t0=(-half[j]-oo)*inv, t1=(half[j]-oo)*inv;
    tlo=fmaxf(tlo,fminf(t0,t1)); thi=fminf(thi,fmaxf(t0,t1));
  }
  bool valid = thi >= fmaxf(tlo,0.f);
  return valid ? tlo : INFINITY;
}

// ============================= k0: pose inverse + ray-box =============================
__global__ __launch_bounds__(64) void k0_setup(
  const float* __restrict__ rays_o, const float* __restrict__ rays_d,
  const float* __restrict__ pose, const float* __restrict__ dimv,
  float* __restrict__ wsf)
{
  __shared__ float Ri[9], tr[3];
  int tid=threadIdx.x; int ray=blockIdx.x*64+tid;
  if(tid==0){
    float P[16];
    for(int j=0;j<16;j++) P[j]=pose[j];
    float a00=P[0],a01=P[1],a02=P[2],a10=P[4],a11=P[5],a12=P[6],a20=P[8],a21=P[9],a22=P[10];
    float c00=a11*a22-a12*a21, c01=a12*a20-a10*a22, c02=a10*a21-a11*a20;
    float det=a00*c00+a01*c01+a02*c02;
    float id=1.f/det;
    Ri[0]=c00*id; Ri[1]=(a02*a21-a01*a22)*id; Ri[2]=(a01*a12-a02*a11)*id;
    Ri[3]=c01*id; Ri[4]=(a00*a22-a02*a20)*id; Ri[5]=(a02*a10-a00*a12)*id;
    Ri[6]=c02*id; Ri[7]=(a01*a20-a00*a21)*id; Ri[8]=(a00*a11-a01*a10)*id;
    float t0=P[3],t1=P[7],t2=P[11];
    tr[0]=-(Ri[0]*t0+Ri[1]*t1+Ri[2]*t2);
    tr[1]=-(Ri[3]*t0+Ri[4]*t1+Ri[5]*t2);
    tr[2]=-(Ri[6]*t0+Ri[7]*t1+Ri[8]*t2);
    if(blockIdx.x==0){
      for(int j=0;j<9;j++) wsf[OFF_RI+j]=Ri[j];
      for(int j=0;j<3;j++) wsf[OFF_TR+j]=tr[j];
    }
  }
  __syncthreads();
  float o3[3],d3[3],dim[3],half[3];
  for(int j=0;j<3;j++){ o3[j]=rays_o[ray*3+j]; d3[j]=rays_d[ray*3+j];
                        dim[j]=dimv[j]; half[j]=0.5f*dim[j]; }
  float tnear=ray_box(Ri,tr,o3,d3,half);
  float tmax=tnear+10.f*(fabsf(dim[0])+fabsf(dim[1])+fabsf(dim[2]));
  float pm[3]={o3[0]+tmax*d3[0], o3[1]+tmax*d3[1], o3[2]+tmax*d3[2]};
  float nd[3]={-d3[0],-d3[1],-d3[2]};
  float tfar=tmax-ray_box(Ri,tr,pm,nd,half);
  bool mm = isfinite(tnear)&&isfinite(tfar)&&(tfar>tnear);
  wsf[OFF_M+ray]=mm?1.f:0.f;
  wsf[OFF_TN+ray]=mm?tnear:0.f;
  wsf[OFF_TF+ray]=mm?tfar:1.f;
  for(int j=0;j<3;j++)
    wsf[OFF_RDO+(size_t)ray*3+j]=Ri[j*3+0]*d3[0]+Ri[j*3+1]*d3[1]+Ri[j*3+2]*d3[2];
}

// ============================= k1: sampling + interp + stable sort =============================
__global__ __launch_bounds__(128) void k1_sample(
  const float* __restrict__ rays_o, const float* __restrict__ rays_d, const float* __restrict__ dimv,
  const float* __restrict__ voxel, const float* __restrict__ fvol,
  const float* __restrict__ u_p, const float* __restrict__ u_cat, const float* __restrict__ u_lam,
  float* __restrict__ wsf)
{
  int i=blockIdx.x, tid=threadIdx.x;
  __shared__ float Ri[9], tr[3], dim[3], o3[3], d3[3];
  __shared__ float t_all[S], occ_all[S], crd_sh[S][3];
  __shared__ int   coff[S][8];
  __shared__ float cww[S][3];
  __shared__ float cdf[SP];
  __shared__ float totv;
  __shared__ int   rnk[S];
  if(tid<9) Ri[tid]=wsf[OFF_RI+tid];
  if(tid<3){ tr[tid]=wsf[OFF_TR+tid]; dim[tid]=dimv[tid];
             o3[tid]=rays_o[i*3+tid]; d3[tid]=rays_d[i*3+tid]; }
  __syncthreads();
  float tn=wsf[OFF_TN+i], tf=wsf[OFF_TF+i];

  auto do_sample=[&](int s, float t){
    float px=o3[0]+t*d3[0], py=o3[1]+t*d3[1], pz=o3[2]+t*d3[2];
    float q0=Ri[0]*px+Ri[1]*py+Ri[2]*pz+tr[0];
    float q1=Ri[3]*px+Ri[4]*py+Ri[5]*pz+tr[1];
    float q2=Ri[6]*px+Ri[7]*py+Ri[8]*pz+tr[2];
    float cz=(0.5f+q2/dim[2])*31.f;
    float cy=(0.5f+q1/dim[1])*31.f;
    float cx=(0.5f+q0/dim[0])*31.f;
    crd_sh[s][0]=cz; crd_sh[s][1]=cy; crd_sh[s][2]=cx;
    Corn Cn; make_corners(cz,cy,cx,Cn);
    for(int q=0;q<8;q++) coff[s][q]=Cn.off[q];
    cww[s][0]=Cn.wz; cww[s][1]=Cn.wy; cww[s][2]=Cn.wx;
    occ_all[s]=interp1(voxel,Cn);
    t_all[s]=t;
  };

  if(tid<SP){
    float u=u_p[i*SP+tid];
    float t=tn+(tf-tn)*((float)tid+u)*(1.f/64.f);
    do_sample(tid,t);
  }
  __syncthreads();
  if(tid==0){
    float c=0;
    for(int j=0;j<SP-1;j++){ float pr=occ_all[j]+occ_all[j+1]; pr=fmaxf(pr,1e-12f); c+=pr; cdf[j]=c; }
    totv=c;
  }
  __syncthreads();
  if(tid<SP-1) cdf[tid]=cdf[tid]/totv;
  __syncthreads();
  if(tid<SI){
    float u=u_cat[i*SI+tid];
    int cnt=0;
    for(int j=0;j<SP-1;j++) cnt += (u>=cdf[j])?1:0;
    int ind=(cnt<SP-2)?cnt:(SP-2);
    float lam=u_lam[i*SI+tid];
    float tfine=lam*t_all[ind]+(1.f-lam)*t_all[ind+1];
    do_sample(SP+tid,tfine);
  }
  __syncthreads();
  if(tid<S){  // stable counting-rank sort (== stable argsort)
    float ts=t_all[tid]; int r=0;
    for(int j=0;j<S;j++){ float tj=t_all[j]; r += (tj<ts || (tj==ts && j<tid)) ? 1:0; }
    rnk[tid]=r;
    size_t base=(size_t)i*S+r;
    wsf[OFF_TS+base]=ts;
    wsf[OFF_OCCS+base]=occ_all[tid];
    wsf[OFF_CRD+base*3+0]=crd_sh[tid][0];
    wsf[OFF_CRD+base*3+1]=crd_sh[tid][1];
    wsf[OFF_CRD+base*3+2]=crd_sh[tid][2];
  }
  __syncthreads();
  for(int idx=tid; idx<S*CIN; idx+=128){
    int s=idx>>5, c=idx&31;
    float wz=cww[s][0], wy=cww[s][1], wx=cww[s][2];
    const float* vc=fvol+(size_t)c*32768;
    float v000=vc[coff[s][0]], v001=vc[coff[s][1]];
    float v010=vc[coff[s][2]], v011=vc[coff[s][3]];
    float v100=vc[coff[s][4]], v101=vc[coff[s][5]];
    float v110=vc[coff[s][6]], v111=vc[coff[s][7]];
    float c00=v000*(1.f-wx)+v001*wx, c01=v010*(1.f-wx)+v011*wx;
    float c10=v100*(1.f-wx)+v101*wx, c11=v110*(1.f-wx)+v111*wx;
    float val=(c00*(1.f-wy)+c01*wy)*(1.f-wz)+(c10*(1.f-wy)+c11*wy)*wz;
    wsf[OFF_XS+((size_t)i*S+rnk[s])*CIN+c]=val;
  }
}

// ============================= k2: sigma MLP, alpha, outputs 0..2 =============================
__global__ __launch_bounds__(128) void k2_sigma(
  const float* __restrict__ dW1, const float* __restrict__ db1,
  const float* __restrict__ dW2, const float* __restrict__ db2,
  float* __restrict__ wsf, float* __restrict__ out)
{
  int t=blockIdx.x, tid=threadIdx.x, i=t/S;
  __shared__ float xx[33];
  __shared__ float part[2];
  if(tid<32) xx[tid]=wsf[OFF_XS+(size_t)t*32+tid];
  if(tid==32) xx[32]=wsf[OFF_OCCS+t];
  __syncthreads();
  float acc=db1[tid];
  for(int k=0;k<33;k++) acc=fmaf(xx[k], dW1[k*C+tid], acc);
  acc = acc>=0.f?acc:0.01f*acc;
  float g = acc*dW2[tid];
  for(int off=32;off;off>>=1) g+=__shfl_down(g,off,64);
  if((tid&63)==0) part[tid>>6]=g;
  __syncthreads();
  if(tid==0){
    float z=part[0]+part[1]+db2[0];
    float sg=1.f/(1.f+expf(-z));
    float occ=xx[32];
    float occt=occ<0.7f?0.f:occ;
    float alpha=occt*sg;
    float m=wsf[OFF_M+i];
    float ts=wsf[OFF_TS+t];
    out[t]      =m!=0.f?ts:0.f;
    out[NT+t]   =m!=0.f?alpha:0.f;
    out[2*NT+t] =m!=0.f?occt:0.f;
    wsf[OFF_OCCT+t]=occt;
  }
}

// ============================= weight prep: fp32 KxN -> bf16 N x Kpad (B^T) =============================
__global__ __launch_bounds__(256) void k_wprep(
  const float* __restrict__ w0, const float* __restrict__ nqkv, const float* __restrict__ no_,
  const float* __restrict__ nf1, const float* __restrict__ nf2,
  const float* __restrict__ rqkv, const float* __restrict__ ro_,
  const float* __restrict__ rf1, const float* __restrict__ rf2,
  short* __restrict__ WT)
{
  int gid = blockIdx.x*256+threadIdx.x;
  if(gid>=(int)WT_TOT) return;
  const float* src; int K,N,Kp; int base;
  if(gid<8192){src=w0;K=42;N=128;Kp=64;base=0;}
  else if(gid<57344){src=nqkv;K=128;N=384;Kp=128;base=8192;}
  else if(gid<73728){src=no_;K=128;N=128;Kp=128;base=57344;}
  else if(gid<106496){src=nf1;K=128;N=256;Kp=128;base=73728;}
  else if(gid<139264){src=nf2;K=256;N=128;Kp=256;base=106496;}
  else if(gid<188416){src=rqkv;K=128;N=384;Kp=128;base=139264;}
  else if(gid<204800){src=ro_;K=128;N=128;Kp=128;base=188416;}
  else if(gid<237568){src=rf1;K=128;N=256;Kp=128;base=204800;}
  else {src=rf2;K=256;N=128;Kp=256;base=237568;}
  int local=gid-base; int n=local/Kp, k=local%Kp;
  WT[gid] = (k<K)? f2s(src[(size_t)k*N+n]) : (short)0;
}

// ============================= xx2 builder: X2 (rows x 64 bf16, cols42..63=0) =============================
__global__ __launch_bounds__(64) void k_build(
  const float* __restrict__ fvhr, const float* __restrict__ wsf,
  short* __restrict__ X2, int tok0)
{
  int tloc=blockIdx.x, tid=threadIdx.x;
  int t=tok0+tloc, i=t/S;
  __shared__ float hr[KHR][6];
  __shared__ float xf[32];
  __shared__ float RiS[9];
  __shared__ float geo[4];
  __shared__ float crd[3];
  if(tid<9) RiS[tid]=wsf[OFF_RI+tid];
  if(tid>=16&&tid<19) crd[tid-16]=wsf[OFF_CRD+(size_t)t*3+(tid-16)];
  if(tid>=32) xf[tid-32]=wsf[OFF_XS+(size_t)t*32+(tid-32)];
  if(tid==9) geo[0]=wsf[OFF_OCCT+t];
  if(tid>=12&&tid<15) geo[1+(tid-12)]=wsf[OFF_RDO+(size_t)i*3+(tid-12)];
  __syncthreads();
  if(tid<48){
    int k=tid/6, ch=tid%6;
    Corn Cn; make_corners(crd[0],crd[1],crd[2],Cn);
    hr[k][ch]=interp1(fvhr+(size_t)(k*6+ch)*32768, Cn);
  }
  __syncthreads();
  for(int idx=tid; idx<512; idx+=64){
    int k=idx>>6, j=idx&63; float v;
    if(j<32) v=xf[j];
    else if(j<35) v=hr[k][j-32];
    else if(j<38){int r=j-35; v=hr[k][3]*RiS[r*3+0]+hr[k][4]*RiS[r*3+1]+hr[k][5]*RiS[r*3+2];}
    else if(j<41) v=geo[1+(j-38)];
    else if(j==41) v=geo[0];
    else v=0.f;
    X2[(size_t)(tloc*8+k)*64 + j]=f2s(v);
  }
}

// ============================= MFMA GEMM: C = [LN?](A) @ Bt^T + bias [+lrelu] [+resid] =============================
// Grid: x = N-tiles (fast-varying -> same-A-tile blocks adjacent), y = M-tiles.
template<int K, bool LNA, bool ACT, bool RESID>
__global__ __launch_bounds__(256) void gemm_ln(
  const short* __restrict__ A, const short* __restrict__ Bt,
  const float* __restrict__ bias, const short* __restrict__ Rres,
  short* __restrict__ Cg, int N)
{
  static_assert(!LNA || K==128, "LNA requires K==128");
  constexpr int KSA = (K<128)?K:128;
  constexpr int NSA = K/KSA;
  constexpr int LDA = KSA+8;
  constexpr int LDB = 64+8;
  __shared__ short Al[128*LDA];
  __shared__ short Bl[128*LDB];
  const int tid=threadIdx.x;
  const int bm=blockIdx.y*128, bn=blockIdx.x*128;
  const int lane=tid&63, wave=tid>>6;
  const int wm=(wave>>1)*64, wn=(wave&1)*64;
  const int quad=lane>>4, m16=lane&15;
  f32x4 acc[4][4];
  for(int a=0;a<4;a++) for(int b=0;b<4;b++) acc[a][b]=(f32x4){0.f,0.f,0.f,0.f};

  for(int sa=0; sa<NSA; ++sa){
    if(sa>0) __syncthreads();
    constexpr int CH8=KSA/8;
    for(int it=0; it<(128*CH8)/256; ++it){
      int li=it*256+tid; int row=li/CH8, kc=li%CH8;
      short8 v = *(const short8*)(A + (size_t)(bm+row)*K + sa*KSA + kc*8);
      if constexpr(LNA){
        float f[8]; float ls=0.f,lq=0.f;
        for(int e=0;e<8;e++){ f[e]=s2f(v[e]); ls+=f[e]; lq+=f[e]*f[e]; }
        for(int off=8;off;off>>=1){ ls+=__shfl_xor(ls,off,16); lq+=__shfl_xor(lq,off,16); }
        float mu=ls*(1.f/128.f);
        float var=lq*(1.f/128.f)-mu*mu;
        float rs=rsqrtf(var+1e-5f);
        for(int e=0;e<8;e++) v[e]=f2s((f[e]-mu)*rs);
      }
      *(short8*)&Al[row*LDA+kc*8]=v;
    }
    __syncthreads();
    for(int sb=0; sb<KSA/64; ++sb){
      if(sb>0) __syncthreads();
      for(int it=0; it<4; ++it){
        int li=it*256+tid; int row=li>>3, kc=li&7;
        *(short8*)&Bl[row*LDB+kc*8] =
          *(const short8*)(Bt + (size_t)(bn+row)*K + sa*KSA + sb*64 + kc*8);
      }
      __syncthreads();
      for(int kk=0; kk<64; kk+=32){
        int ka = sb*64+kk;
        short8 af[4], bfv[4];
        for(int im=0; im<4; im++)
          af[im] = *(const short8*)&Al[(wm+im*16+m16)*LDA + ka + quad*8];
        for(int in=0; in<4; in++)
          bfv[in] = *(const short8*)&Bl[(wn+in*16+m16)*LDB + kk + quad*8];
        for(int im=0;im<4;im++)
          for(int in=0;in<4;in++)
            acc[im][in] = __builtin_amdgcn_mfma_f32_16x16x32_bf16(af[im], bfv[in], acc[im][in], 0,0,0);
      }
    }
  }
  // epilogue
  for(int in=0;in<4;in++){
    int col = bn + wn + in*16 + m16;
    float bv = bias[col];
    for(int im=0;im<4;im++){
      for(int r=0;r<4;r++){
        int grow = bm + wm + im*16 + quad*4 + r;
        float v = acc[im][in][r] + bv;
        if constexpr(ACT) v = v>=0.f? v : 0.01f*v;
        if constexpr(RESID) v += s2f(Rres[(size_t)grow*N + col]);
        Cg[(size_t)grow*N + col] = f2s(v);
      }
    }
  }
}

// ============================= nf attention: K=8 tokens (padded LDS) =============================
__global__ __launch_bounds__(256) void nf_attn(const short* __restrict__ qkv, short* __restrict__ att){
  constexpr int QLD=392;  // 196 words; 196%32=4 -> conflict-free spread
  __shared__ short Qs[4*8*QLD];
  int t0=blockIdx.x*4, tid=threadIdx.x;
  for(int li=tid; li<1536; li+=256){
    int e=li*8;
    int tok=e/3072, rem=e-tok*3072;
    int j=rem/384, k=rem-j*384;
    *(short8*)&Qs[(tok*8+j)*QLD + k] = *(const short8*)(qkv + (size_t)t0*3072 + e);
  }
  __syncthreads();
  int lt=tid>>6, lane=tid&63;
  int h=lane>>3, q=lane&7;
  const short* base = &Qs[(lt*8)*QLD + h*16];
  float qv[16];
  for(int d=0;d<16;d++) qv[d]=s2f(base[q*QLD+d]);
  float sc[8]; float mx=-INFINITY;
  for(int j=0;j<8;j++){
    float a=0;
    for(int d=0;d<16;d++) a+=qv[d]*s2f(base[j*QLD+128+d]);
    a*=0.25f; sc[j]=a; mx=fmaxf(mx,a);
  }
  float se=0;
  for(int j=0;j<8;j++){ sc[j]=expf(sc[j]-mx); se+=sc[j]; }
  float inv=1.f/se;
  float o[16];
  for(int d=0;d<16;d++) o[d]=0.f;
  for(int j=0;j<8;j++){
    float p=sc[j];
    for(int d=0;d<16;d++) o[d]+=p*s2f(base[j*QLD+256+d]);
  }
  short* ob = att + (size_t)(t0*8 + lt*8 + q)*128 + h*16;
  for(int d=0;d<16;d++) ob[d]=f2s(o[d]*inv);
}

// ============================= rt attention: 4 heads/block, 3 q-rows/thread =============================
__global__ __launch_bounds__(128) void rt_attn(const short* __restrict__ qkvb, short* __restrict__ attout){
  int b=blockIdx.x; int i=b&255, h0=(b>>8)*4; int tid=threadIdx.x;
  __shared__ float kh[96][64], vh[96][64];   // 49152 B
  for(int idx=tid; idx<1536; idx+=128){
    int kv = idx>=768; int l = idx - (kv<<9) - (kv<<8);  // idx - kv*768
    int j = l>>3, c = l&7;
    size_t base = ((size_t)(i*96+j))*384 + h0*16 + (kv?256:128) + c*8;
    short8 x = *(const short8*)(qkvb+base);
    float* dst = kv? &vh[j][c*8] : &kh[j][c*8];
    for(int e=0;e<8;e++) dst[e]=s2f(x[e]);
  }
  __syncthreads();
  int hh=tid>>5, lq=tid&31, h=h0+hh, r0=lq*3;
  float q[3][16];
  for(int rr=0;rr<3;rr++){
    size_t qb=((size_t)(i*96+r0+rr))*384 + h*16;
    short8 a=*(const short8*)(qkvb+qb), bq=*(const short8*)(qkvb+qb+8);
    for(int e=0;e<8;e++){ q[rr][e]=s2f(a[e]); q[rr][8+e]=s2f(bq[e]); }
  }
  float acc[3][16]; float se0=0.f,se1=0.f,se2=0.f;
  for(int rr=0;rr<3;rr++) for(int d=0;d<16;d++) acc[rr][d]=0.f;
  const float* kbase=&kh[0][hh*16];
  const float* vbase=&vh[0][hh*16];
  for(int j=0;j<96;j++){
    const float* kj = kbase + j*64;
    float s0=0.f,s1=0.f,s2=0.f;
    for(int d=0;d<16;d++){ float kv_=kj[d];
      s0=fmaf(q[0][d],kv_,s0); s1=fmaf(q[1][d],kv_,s1); s2=fmaf(q[2][d],kv_,s2); }
    float p0=expf(s0*0.25f), p1=expf(s1*0.25f), p2=expf(s2*0.25f);
    se0+=p0; se1+=p1; se2+=p2;
    const float* vj = vbase + j*64;
    for(int d=0;d<16;d++){ float vv=vj[d];
      acc[0][d]=fmaf(p0,vv,acc[0][d]); acc[1][d]=fmaf(p1,vv,acc[1][d]); acc[2][d]=fmaf(p2,vv,acc[2][d]); }
  }
  float inv[3]={1.f/se0, 1.f/se1, 1.f/se2};
  for(int rr=0;rr<3;rr++){
    short8 o0,o1;
    for(int e=0;e<8;e++){ o0[e]=f2s(acc[rr][e]*inv[rr]); o1[e]=f2s(acc[rr][8+e]*inv[rr]); }
    size_t ob=((size_t)(i*96+r0+rr))*128 + h*16;
    *(short8*)(attout+ob)=o0;
    *(short8*)(attout+ob+8)=o1;
  }
}

// ============================= radiance head =============================
__global__ __launch_bounds__(256) void k_rad(
  const short* __restrict__ h3, const float* __restrict__ fW, const float* __restrict__ fb,
  const float* __restrict__ wsf, float* __restrict__ out)
{
  int t=blockIdx.x*256+threadIdx.x;
  if(t>=NT) return;
  int i=t/S;
  float a0=fb[0], a1=fb[1], a2=fb[2];
  for(int c=0;c<C;c++){
    float hv=s2f(h3[(size_t)t*C+c]);
    a0=fmaf(hv,fW[c*3+0],a0);
    a1=fmaf(hv,fW[c*3+1],a1);
    a2=fmaf(hv,fW[c*3+2],a2);
  }
  float m=wsf[OFF_M+i];
  float r0=1.f/(1.f+expf(-a0)), r1=1.f/(1.f+expf(-a1)), r2=1.f/(1.f+expf(-a2));
  size_t ob=3*(size_t)NT+(size_t)t*3;
  out[ob+0]=m!=0.f?r0:0.f;
  out[ob+1]=m!=0.f?r1:0.f;
  out[ob+2]=m!=0.f?r2:0.f;
}

// ============================= mean over KHR=8 -> h2 =============================
__global__ __launch_bounds__(256) void k_mean(const short* __restrict__ x2o, short* __restrict__ h2){
  int bt = blockIdx.x*2 + (threadIdx.x>>7);
  int c = threadIdx.x&127;
  float s=0;
  for(int k=0;k<8;k++) s += s2f(x2o[(size_t)(bt*8+k)*128 + c]);
  h2[(size_t)bt*128+c] = f2s(s*0.125f);
}

extern "C" void kernel_launch(void* const* d_in, const int* in_sizes, int n_in,
                              void* d_out, int out_size, void* d_ws, size_t ws_size,
                              hipStream_t stream) {
  (void)in_sizes; (void)n_in; (void)out_size;
  const float* rays_o =(const float*)d_in[0];
  const float* rays_d =(const float*)d_in[1];
  const float* pose   =(const float*)d_in[2];
  const float* dimv   =(const float*)d_in[3];
  const float* voxel  =(const float*)d_in[4];
  const float* fvol   =(const float*)d_in[5];
  const float* fvhr   =(const float*)d_in[6];
  const float* u_p    =(const float*)d_in[7];
  const float* u_cat  =(const float*)d_in[8];
  const float* u_lam  =(const float*)d_in[9];
  const float* dW1    =(const float*)d_in[10];
  const float* db1    =(const float*)d_in[11];
  const float* dW2    =(const float*)d_in[12];
  const float* db2    =(const float*)d_in[13];
  const float* rW0    =(const float*)d_in[14];
  const float* rb0    =(const float*)d_in[15];
  const float* nf_qkv =(const float*)d_in[16];
  const float* nf_qkvb=(const float*)d_in[17];
  const float* nf_o   =(const float*)d_in[18];
  const float* nf_ob  =(const float*)d_in[19];
  const float* nf_f1  =(const float*)d_in[20];
  const float* nf_f1b =(const float*)d_in[21];
  const float* nf_f2  =(const float*)d_in[22];
  const float* nf_f2b =(const float*)d_in[23];
  const float* rt_qkv =(const float*)d_in[24];
  const float* rt_qkvb=(const float*)d_in[25];
  const float* rt_o   =(const float*)d_in[26];
  const float* rt_ob  =(const float*)d_in[27];
  const float* rt_f1  =(const float*)d_in[28];
  const float* rt_f1b =(const float*)d_in[29];
  const float* rt_f2  =(const float*)d_in[30];
  const float* rt_f2b =(const float*)d_in[31];
  const float* fW     =(const float*)d_in[32];
  const float* fb     =(const float*)d_in[33];

  float* wsf=(float*)d_ws;
  short* wsb=(short*)((char*)d_ws + F32_CNT*4);
  float* out=(float*)d_out;

  // Chunking: arena <= 160 MB (L3-resident incl. weights/H2) -> nch=2.
  // nch=1 (252 MB) thrashed L3 (161 MB FETCH/gemm); nch=4 starved the grid.
  int nch=1;
  while(nch<8 && ((size_t)MTOT/nch)*640ULL*2ULL > (160ULL<<20)) nch<<=1;
  for(; nch<8; nch<<=1){
    size_t mc_=(size_t)MTOT/nch;
    size_t region=mc_*640ULL; if(region<RT_TOT) region=RT_TOT;
    size_t need=F32_CNT*4 + 2ULL*(CHB + region);
    if(need <= ws_size) break;
  }
  const size_t mc = (size_t)MTOT/nch;
  const int Tc = (int)(mc/8);

  short* WT  = wsb;
  short* H2  = wsb + H2OFF;
  short* arena = wsb + CHB;
  // nf chunk overlays: h0[0,128) qkv[128,512) att/f2out[512,640) x2[512,576)
  // x1[128,256) f1[256,512)
  short* o_h0 = arena;
  short* o_qkv= arena + (size_t)128*mc;
  short* o_x1 = arena + (size_t)128*mc;
  short* o_f1 = arena + (size_t)256*mc;
  short* o_att= arena + (size_t)512*mc;
  short* o_x2 = arena + (size_t)512*mc;
  short* o_f2 = arena + (size_t)512*mc;
  // rt overlays: qkv[0,384) att/h3[384,512) x[0,128) f1[128,384)
  short* r_qkv= arena;
  short* r_att= arena + (size_t)384*NT;
  short* r_x  = arena;
  short* r_f1 = arena + (size_t)128*NT;
  short* r_h3 = arena + (size_t)384*NT;

  k0_setup<<<NRAY/64,64,0,stream>>>(rays_o,rays_d,pose,dimv,wsf);
  k1_sample<<<NRAY,128,0,stream>>>(rays_o,rays_d,dimv,voxel,fvol,u_p,u_cat,u_lam,wsf);
  k2_sigma<<<NT,128,0,stream>>>(dW1,db1,dW2,db2,wsf,out);
  k_wprep<<<(int)((WT_TOT+255)/256),256,0,stream>>>(rW0,nf_qkv,nf_o,nf_f1,nf_f2,rt_qkv,rt_o,rt_f1,rt_f2,WT);

  const int mt=(int)(mc/128);
  for(int ch=0; ch<nch; ++ch){
    int tok0 = ch*Tc;
    k_build<<<Tc,64,0,stream>>>(fvhr, wsf, o_x2, tok0);
    gemm_ln< 64,false,false,false><<<dim3(1,mt),256,0,stream>>>(o_x2, WT+WT_W0,  rb0,     nullptr, o_h0, 128);
    gemm_ln<128,true ,false,false><<<dim3(3,mt),256,0,stream>>>(o_h0, WT+WT_NQKV,nf_qkvb, nullptr, o_qkv,384);
    nf_attn<<<Tc/4,256,0,stream>>>(o_qkv, o_att);
    gemm_ln<128,false,false,true ><<<dim3(1,mt),256,0,stream>>>(o_att,WT+WT_NO,  nf_ob,   o_h0,    o_x1, 128);
    gemm_ln<128,true ,true ,false><<<dim3(2,mt),256,0,stream>>>(o_x1, WT+WT_NF1, nf_f1b,  nullptr, o_f1, 256);
    gemm_ln<256,false,false,true ><<<dim3(1,mt),256,0,stream>>>(o_f1, WT+WT_NF2, nf_f2b,  o_x1,    o_f2, 128);
    k_mean<<<Tc/2,256,0,stream>>>(o_f2, H2 + (size_t)tok0*128);
  }

  gemm_ln<128,true ,false,false><<<dim3(3,NT/128),256,0,stream>>>(H2,   WT+WT_RQKV,rt_qkvb, nullptr, r_qkv,384);
  rt_attn<<<NRAY*2,128,0,stream>>>(r_qkv, r_att);
  gemm_ln<128,false,false,true ><<<dim3(1,NT/128),256,0,stream>>>(r_att,WT+WT_RO,  rt_ob,   H2,      r_x,  128);
  gemm_ln<128,true ,true ,false><<<dim3(2,NT/128),256,0,stream>>>(r_x,  WT+WT_RF1, rt_f1b,  nullptr, r_f1, 256);
  gemm_ln<256,false,false,true ><<<dim3(1,NT/128),256,0,stream>>>(r_f1, WT+WT_RF2, rt_f2b,  r_x,     r_h3, 128);
  k_rad<<<NT/256,256,0,stream>>>(r_h3, fW, fb, wsf, out);
}

// Round 9
// 536.276 us; speedup vs baseline: 1.3319x; 1.1638x over previous
//
#include <hip/hip_runtime.h>
#include <hip/hip_bf16.h>
#include <cmath>

// Inputs/outputs float32. Geometry/sampling fp32 (k0/k1/k2). nf + rt chains as
// bf16 MFMA GEMMs (fp32 accum), LN fused into A-staging, bias/lrelu/residual
// in epilogue. Chunking: smallest nch that fits ws (nch=1 measured fastest:
// launch/tail cost of chunking > L3-thrash cost). rt_attn: 2-way key split
// in-block (8 waves/CU). k_mean fused into f2 GEMM epilogue (MEAN flag).

using bf16 = __hip_bfloat16;
#define DEV __device__ __forceinline__

typedef __attribute__((ext_vector_type(8))) short short8;
typedef __attribute__((ext_vector_type(4))) float f32x4;

DEV float s2f(short s){ unsigned u=((unsigned)(unsigned short)s)<<16; float f; __builtin_memcpy(&f,&u,4); return f; }
DEV short f2s(float f){ bf16 h=__float2bfloat16(f); short r; __builtin_memcpy(&r,&h,2); return r; }

constexpr int NRAY=256, SP=64, SI=32, S=96, KHR=8, CIN=32, C=128, NH=8, DH=16;
constexpr int NT = NRAY*S;           // 24576 tokens
constexpr int MTOT = NT*KHR;         // 196608 rows in the nf chain

// ---- fp32 ws region (element offsets) ----
constexpr size_t OFF_RI=0, OFF_TR=9, OFF_M=16, OFF_TN=272, OFF_TF=528, OFF_RDO=784,
  OFF_TS=1552, OFF_OCCS=26128, OFF_OCCT=50704, OFF_CRD=75280, OFF_XS=149008, F32_CNT=935440;

// ---- bf16 ws region (element offsets from bf16 base) ----
constexpr size_t WT_W0=0, WT_NQKV=8192, WT_NO=57344, WT_NF1=73728, WT_NF2=106496,
  WT_RQKV=139264, WT_RO=188416, WT_RF1=204800, WT_RF2=237568, WT_TOT=270336;
constexpr size_t H2OFF=WT_TOT;                 // h2: NT*128
constexpr size_t CHB=H2OFF+(size_t)NT*128;     // chunk / rt arena base
constexpr size_t RT_TOT=(size_t)NT*512;        // compacted rt arena

struct Corn { int off[8]; float wz, wy, wx; };

DEV void make_corners(float cz, float cy, float cx, Corn& Cn){
  cz=fminf(fmaxf(cz,0.f),31.f); cy=fminf(fmaxf(cy,0.f),31.f); cx=fminf(fmaxf(cx,0.f),31.f);
  int z0=(int)cz, y0=(int)cy, x0=(int)cx;
  int z1=(z0+1<31)?z0+1:31, y1=(y0+1<31)?y0+1:31, x1=(x0+1<31)?x0+1:31;
  Cn.wz=cz-(float)z0; Cn.wy=cy-(float)y0; Cn.wx=cx-(float)x0;
  int zy00=z0*1024+y0*32, zy01=z0*1024+y1*32, zy10=z1*1024+y0*32, zy11=z1*1024+y1*32;
  Cn.off[0]=zy00+x0; Cn.off[1]=zy00+x1;
  Cn.off[2]=zy01+x0; Cn.off[3]=zy01+x1;
  Cn.off[4]=zy10+x0; Cn.off[5]=zy10+x1;
  Cn.off[6]=zy11+x0; Cn.off[7]=zy11+x1;
}

DEV float interp1(const float* __restrict__ vol, const Corn& Cn){
  float v000=vol[Cn.off[0]], v001=vol[Cn.off[1]];
  float v010=vol[Cn.off[2]], v011=vol[Cn.off[3]];
  float v100=vol[Cn.off[4]], v101=vol[Cn.off[5]];
  float v110=vol[Cn.off[6]], v111=vol[Cn.off[7]];
  float wx=Cn.wx, wy=Cn.wy, wz=Cn.wz;
  float c00=v000*(1.f-wx)+v001*wx, c01=v010*(1.f-wx)+v011*wx;
  float c10=v100*(1.f-wx)+v101*wx, c11=v110*(1.f-wx)+v111*wx;
  return (c00*(1.f-wy)+c01*wy)*(1.f-wz) + (c10*(1.f-wy)+c11*wy)*wz;
}

DEV float ray_box(const float* Ri, const float* tr, const float* o3, const float* d3, const float* half){
  float tlo=-INFINITY, thi=INFINITY;
  for(int j=0;j<3;j++){
    float oo=Ri[j*3+0]*o3[0]+Ri[j*3+1]*o3[1]+Ri[j*3+2]*o3[2]+tr[j];
    float dd=Ri[j*3+0]*d3[0]+Ri[j*3+1]*d3[1]+Ri[j*3+2]*d3[2];
    if (fabsf(dd)<1e-9f) dd=1e-9f;
    float inv=1.f/dd;
    float t0=(-half[j]-oo)*inv, t1=(half[j]-oo)*inv;
    tlo=fmaxf(tlo,fminf(t0,t1)); thi=fminf(thi,fmaxf(t0,t1));
  }
  bool valid = thi >= fmaxf(tlo,0.f);
  return valid ? tlo : INFINITY;
}

// ============================= k0: pose inverse + ray-box =============================
__global__ __launch_bounds__(64) void k0_setup(
  const float* __restrict__ rays_o, const float* __restrict__ rays_d,
  const float* __restrict__ pose, const float* __restrict__ dimv,
  float* __restrict__ wsf)
{
  __shared__ float Ri[9], tr[3];
  int tid=threadIdx.x; int ray=blockIdx.x*64+tid;
  if(tid==0){
    float P[16];
    for(int j=0;j<16;j++) P[j]=pose[j];
    float a00=P[0],a01=P[1],a02=P[2],a10=P[4],a11=P[5],a12=P[6],a20=P[8],a21=P[9],a22=P[10];
    float c00=a11*a22-a12*a21, c01=a12*a20-a10*a22, c02=a10*a21-a11*a20;
    float det=a00*c00+a01*c01+a02*c02;
    float id=1.f/det;
    Ri[0]=c00*id; Ri[1]=(a02*a21-a01*a22)*id; Ri[2]=(a01*a12-a02*a11)*id;
    Ri[3]=c01*id; Ri[4]=(a00*a22-a02*a20)*id; Ri[5]=(a02*a10-a00*a12)*id;
    Ri[6]=c02*id; Ri[7]=(a01*a20-a00*a21)*id; Ri[8]=(a00*a11-a01*a10)*id;
    float t0=P[3],t1=P[7],t2=P[11];
    tr[0]=-(Ri[0]*t0+Ri[1]*t1+Ri[2]*t2);
    tr[1]=-(Ri[3]*t0+Ri[4]*t1+Ri[5]*t2);
    tr[2]=-(Ri[6]*t0+Ri[7]*t1+Ri[8]*t2);
    if(blockIdx.x==0){
      for(int j=0;j<9;j++) wsf[OFF_RI+j]=Ri[j];
      for(int j=0;j<3;j++) wsf[OFF_TR+j]=tr[j];
    }
  }
  __syncthreads();
  float o3[3],d3[3],dim[3],half[3];
  for(int j=0;j<3;j++){ o3[j]=rays_o[ray*3+j]; d3[j]=rays_d[ray*3+j];
                        dim[j]=dimv[j]; half[j]=0.5f*dim[j]; }
  float tnear=ray_box(Ri,tr,o3,d3,half);
  float tmax=tnear+10.f*(fabsf(dim[0])+fabsf(dim[1])+fabsf(dim[2]));
  float pm[3]={o3[0]+tmax*d3[0], o3[1]+tmax*d3[1], o3[2]+tmax*d3[2]};
  float nd[3]={-d3[0],-d3[1],-d3[2]};
  float tfar=tmax-ray_box(Ri,tr,pm,nd,half);
  bool mm = isfinite(tnear)&&isfinite(tfar)&&(tfar>tnear);
  wsf[OFF_M+ray]=mm?1.f:0.f;
  wsf[OFF_TN+ray]=mm?tnear:0.f;
  wsf[OFF_TF+ray]=mm?tfar:1.f;
  for(int j=0;j<3;j++)
    wsf[OFF_RDO+(size_t)ray*3+j]=Ri[j*3+0]*d3[0]+Ri[j*3+1]*d3[1]+Ri[j*3+2]*d3[2];
}

// ============================= k1: sampling + interp + stable sort =============================
__global__ __launch_bounds__(128) void k1_sample(
  const float* __restrict__ rays_o, const float* __restrict__ rays_d, const float* __restrict__ dimv,
  const float* __restrict__ voxel, const float* __restrict__ fvol,
  const float* __restrict__ u_p, const float* __restrict__ u_cat, const float* __restrict__ u_lam,
  float* __restrict__ wsf)
{
  int i=blockIdx.x, tid=threadIdx.x;
  __shared__ float Ri[9], tr[3], dim[3], o3[3], d3[3];
  __shared__ float t_all[S], occ_all[S], crd_sh[S][3];
  __shared__ int   coff[S][8];
  __shared__ float cww[S][3];
  __shared__ float cdf[SP];
  __shared__ float totv;
  __shared__ int   rnk[S];
  if(tid<9) Ri[tid]=wsf[OFF_RI+tid];
  if(tid<3){ tr[tid]=wsf[OFF_TR+tid]; dim[tid]=dimv[tid];
             o3[tid]=rays_o[i*3+tid]; d3[tid]=rays_d[i*3+tid]; }
  __syncthreads();
  float tn=wsf[OFF_TN+i], tf=wsf[OFF_TF+i];

  auto do_sample=[&](int s, float t){
    float px=o3[0]+t*d3[0], py=o3[1]+t*d3[1], pz=o3[2]+t*d3[2];
    float q0=Ri[0]*px+Ri[1]*py+Ri[2]*pz+tr[0];
    float q1=Ri[3]*px+Ri[4]*py+Ri[5]*pz+tr[1];
    float q2=Ri[6]*px+Ri[7]*py+Ri[8]*pz+tr[2];
    float cz=(0.5f+q2/dim[2])*31.f;
    float cy=(0.5f+q1/dim[1])*31.f;
    float cx=(0.5f+q0/dim[0])*31.f;
    crd_sh[s][0]=cz; crd_sh[s][1]=cy; crd_sh[s][2]=cx;
    Corn Cn; make_corners(cz,cy,cx,Cn);
    for(int q=0;q<8;q++) coff[s][q]=Cn.off[q];
    cww[s][0]=Cn.wz; cww[s][1]=Cn.wy; cww[s][2]=Cn.wx;
    occ_all[s]=interp1(voxel,Cn);
    t_all[s]=t;
  };

  if(tid<SP){
    float u=u_p[i*SP+tid];
    float t=tn+(tf-tn)*((float)tid+u)*(1.f/64.f);
    do_sample(tid,t);
  }
  __syncthreads();
  if(tid==0){
    float c=0;
    for(int j=0;j<SP-1;j++){ float pr=occ_all[j]+occ_all[j+1]; pr=fmaxf(pr,1e-12f); c+=pr; cdf[j]=c; }
    totv=c;
  }
  __syncthreads();
  if(tid<SP-1) cdf[tid]=cdf[tid]/totv;
  __syncthreads();
  if(tid<SI){
    float u=u_cat[i*SI+tid];
    int cnt=0;
    for(int j=0;j<SP-1;j++) cnt += (u>=cdf[j])?1:0;
    int ind=(cnt<SP-2)?cnt:(SP-2);
    float lam=u_lam[i*SI+tid];
    float tfine=lam*t_all[ind]+(1.f-lam)*t_all[ind+1];
    do_sample(SP+tid,tfine);
  }
  __syncthreads();
  if(tid<S){  // stable counting-rank sort (== stable argsort)
    float ts=t_all[tid]; int r=0;
    for(int j=0;j<S;j++){ float tj=t_all[j]; r += (tj<ts || (tj==ts && j<tid)) ? 1:0; }
    rnk[tid]=r;
    size_t base=(size_t)i*S+r;
    wsf[OFF_TS+base]=ts;
    wsf[OFF_OCCS+base]=occ_all[tid];
    wsf[OFF_CRD+base*3+0]=crd_sh[tid][0];
    wsf[OFF_CRD+base*3+1]=crd_sh[tid][1];
    wsf[OFF_CRD+base*3+2]=crd_sh[tid][2];
  }
  __syncthreads();
  for(int idx=tid; idx<S*CIN; idx+=128){
    int s=idx>>5, c=idx&31;
    float wz=cww[s][0], wy=cww[s][1], wx=cww[s][2];
    const float* vc=fvol+(size_t)c*32768;
    float v000=vc[coff[s][0]], v001=vc[coff[s][1]];
    float v010=vc[coff[s][2]], v011=vc[coff[s][3]];
    float v100=vc[coff[s][4]], v101=vc[coff[s][5]];
    float v110=vc[coff[s][6]], v111=vc[coff[s][7]];
    float c00=v000*(1.f-wx)+v001*wx, c01=v010*(1.f-wx)+v011*wx;
    float c10=v100*(1.f-wx)+v101*wx, c11=v110*(1.f-wx)+v111*wx;
    float val=(c00*(1.f-wy)+c01*wy)*(1.f-wz)+(c10*(1.f-wy)+c11*wy)*wz;
    wsf[OFF_XS+((size_t)i*S+rnk[s])*CIN+c]=val;
  }
}

// ============================= k2: sigma MLP, alpha, outputs 0..2 =============================
__global__ __launch_bounds__(128) void k2_sigma(
  const float* __restrict__ dW1, const float* __restrict__ db1,
  const float* __restrict__ dW2, const float* __restrict__ db2,
  float* __restrict__ wsf, float* __restrict__ out)
{
  int t=blockIdx.x, tid=threadIdx.x, i=t/S;
  __shared__ float xx[33];
  __shared__ float part[2];
  if(tid<32) xx[tid]=wsf[OFF_XS+(size_t)t*32+tid];
  if(tid==32) xx[32]=wsf[OFF_OCCS+t];
  __syncthreads();
  float acc=db1[tid];
  for(int k=0;k<33;k++) acc=fmaf(xx[k], dW1[k*C+tid], acc);
  acc = acc>=0.f?acc:0.01f*acc;
  float g = acc*dW2[tid];
  for(int off=32;off;off>>=1) g+=__shfl_down(g,off,64);
  if((tid&63)==0) part[tid>>6]=g;
  __syncthreads();
  if(tid==0){
    float z=part[0]+part[1]+db2[0];
    float sg=1.f/(1.f+expf(-z));
    float occ=xx[32];
    float occt=occ<0.7f?0.f:occ;
    float alpha=occt*sg;
    float m=wsf[OFF_M+i];
    float ts=wsf[OFF_TS+t];
    out[t]      =m!=0.f?ts:0.f;
    out[NT+t]   =m!=0.f?alpha:0.f;
    out[2*NT+t] =m!=0.f?occt:0.f;
    wsf[OFF_OCCT+t]=occt;
  }
}

// ============================= weight prep: fp32 KxN -> bf16 N x Kpad (B^T) =============================
__global__ __launch_bounds__(256) void k_wprep(
  const float* __restrict__ w0, const float* __restrict__ nqkv, const float* __restrict__ no_,
  const float* __restrict__ nf1, const float* __restrict__ nf2,
  const float* __restrict__ rqkv, const float* __restrict__ ro_,
  const float* __restrict__ rf1, const float* __restrict__ rf2,
  short* __restrict__ WT)
{
  int gid = blockIdx.x*256+threadIdx.x;
  if(gid>=(int)WT_TOT) return;
  const float* src; int K,N,Kp; int base;
  if(gid<8192){src=w0;K=42;N=128;Kp=64;base=0;}
  else if(gid<57344){src=nqkv;K=128;N=384;Kp=128;base=8192;}
  else if(gid<73728){src=no_;K=128;N=128;Kp=128;base=57344;}
  else if(gid<106496){src=nf1;K=128;N=256;Kp=128;base=73728;}
  else if(gid<139264){src=nf2;K=256;N=128;Kp=256;base=106496;}
  else if(gid<188416){src=rqkv;K=128;N=384;Kp=128;base=139264;}
  else if(gid<204800){src=ro_;K=128;N=128;Kp=128;base=188416;}
  else if(gid<237568){src=rf1;K=128;N=256;Kp=128;base=204800;}
  else {src=rf2;K=256;N=128;Kp=256;base=237568;}
  int local=gid-base; int n=local/Kp, k=local%Kp;
  WT[gid] = (k<K)? f2s(src[(size_t)k*N+n]) : (short)0;
}

// ============================= xx2 builder: X2 (rows x 64 bf16, cols42..63=0) =============================
__global__ __launch_bounds__(64) void k_build(
  const float* __restrict__ fvhr, const float* __restrict__ wsf,
  short* __restrict__ X2, int tok0)
{
  int tloc=blockIdx.x, tid=threadIdx.x;
  int t=tok0+tloc, i=t/S;
  __shared__ float hr[KHR][6];
  __shared__ float xf[32];
  __shared__ float RiS[9];
  __shared__ float geo[4];
  __shared__ float crd[3];
  if(tid<9) RiS[tid]=wsf[OFF_RI+tid];
  if(tid>=16&&tid<19) crd[tid-16]=wsf[OFF_CRD+(size_t)t*3+(tid-16)];
  if(tid>=32) xf[tid-32]=wsf[OFF_XS+(size_t)t*32+(tid-32)];
  if(tid==9) geo[0]=wsf[OFF_OCCT+t];
  if(tid>=12&&tid<15) geo[1+(tid-12)]=wsf[OFF_RDO+(size_t)i*3+(tid-12)];
  __syncthreads();
  if(tid<48){
    int k=tid/6, ch=tid%6;
    Corn Cn; make_corners(crd[0],crd[1],crd[2],Cn);
    hr[k][ch]=interp1(fvhr+(size_t)(k*6+ch)*32768, Cn);
  }
  __syncthreads();
  for(int idx=tid; idx<512; idx+=64){
    int k=idx>>6, j=idx&63; float v;
    if(j<32) v=xf[j];
    else if(j<35) v=hr[k][j-32];
    else if(j<38){int r=j-35; v=hr[k][3]*RiS[r*3+0]+hr[k][4]*RiS[r*3+1]+hr[k][5]*RiS[r*3+2];}
    else if(j<41) v=geo[1+(j-38)];
    else if(j==41) v=geo[0];
    else v=0.f;
    X2[(size_t)(tloc*8+k)*64 + j]=f2s(v);
  }
}

// ============================= MFMA GEMM: C = [LN?](A) @ Bt^T + bias [+lrelu] [+resid] [mean8->H2] =====
// Grid: x = M-tiles (round-6 measured-best order), y = N-tiles.
// MEAN: instead of writing C, reduce each token's 8 consecutive rows and write
// H2[tok][col] = mean (k_mean fused; f2 output never materialized).
template<int K, bool LNA, bool ACT, bool RESID, bool MEAN=false>
__global__ __launch_bounds__(256) void gemm_ln(
  const short* __restrict__ A, const short* __restrict__ Bt,
  const float* __restrict__ bias, const short* __restrict__ Rres,
  short* __restrict__ Cg, int N)
{
  static_assert(!LNA || K==128, "LNA requires K==128");
  constexpr int KSA = (K<128)?K:128;
  constexpr int NSA = K/KSA;
  constexpr int LDA = KSA+8;
  constexpr int LDB = 64+8;
  __shared__ short Al[128*LDA];
  __shared__ short Bl[128*LDB];
  const int tid=threadIdx.x;
  const int bm=blockIdx.x*128, bn=blockIdx.y*128;
  const int lane=tid&63, wave=tid>>6;
  const int wm=(wave>>1)*64, wn=(wave&1)*64;
  const int quad=lane>>4, m16=lane&15;
  f32x4 acc[4][4];
  for(int a=0;a<4;a++) for(int b=0;b<4;b++) acc[a][b]=(f32x4){0.f,0.f,0.f,0.f};

  for(int sa=0; sa<NSA; ++sa){
    if(sa>0) __syncthreads();
    constexpr int CH8=KSA/8;
    for(int it=0; it<(128*CH8)/256; ++it){
      int li=it*256+tid; int row=li/CH8, kc=li%CH8;
      short8 v = *(const short8*)(A + (size_t)(bm+row)*K + sa*KSA + kc*8);
      if constexpr(LNA){
        float f[8]; float ls=0.f,lq=0.f;
        for(int e=0;e<8;e++){ f[e]=s2f(v[e]); ls+=f[e]; lq+=f[e]*f[e]; }
        for(int off=8;off;off>>=1){ ls+=__shfl_xor(ls,off,16); lq+=__shfl_xor(lq,off,16); }
        float mu=ls*(1.f/128.f);
        float var=lq*(1.f/128.f)-mu*mu;
        float rs=rsqrtf(var+1e-5f);
        for(int e=0;e<8;e++) v[e]=f2s((f[e]-mu)*rs);
      }
      *(short8*)&Al[row*LDA+kc*8]=v;
    }
    __syncthreads();
    for(int sb=0; sb<KSA/64; ++sb){
      if(sb>0) __syncthreads();
      for(int it=0; it<4; ++it){
        int li=it*256+tid; int row=li>>3, kc=li&7;
        *(short8*)&Bl[row*LDB+kc*8] =
          *(const short8*)(Bt + (size_t)(bn+row)*K + sa*KSA + sb*64 + kc*8);
      }
      __syncthreads();
      for(int kk=0; kk<64; kk+=32){
        int ka = sb*64+kk;
        short8 af[4], bfv[4];
        for(int im=0; im<4; im++)
          af[im] = *(const short8*)&Al[(wm+im*16+m16)*LDA + ka + quad*8];
        for(int in=0; in<4; in++)
          bfv[in] = *(const short8*)&Bl[(wn+in*16+m16)*LDB + kk + quad*8];
        for(int im=0;im<4;im++)
          for(int in=0;in<4;in++)
            acc[im][in] = __builtin_amdgcn_mfma_f32_16x16x32_bf16(af[im], bfv[in], acc[im][in], 0,0,0);
      }
    }
  }
  // epilogue
  for(int in=0;in<4;in++){
    int col = bn + wn + in*16 + m16;
    float bv = bias[col];
    for(int im=0;im<4;im++){
      if constexpr(MEAN){
        float s4=0.f;
        for(int r=0;r<4;r++){
          int grow = bm + wm + im*16 + quad*4 + r;
          float v = acc[im][in][r] + bv;
          if constexpr(RESID) v += s2f(Rres[(size_t)grow*N + col]);
          s4 += v;
        }
        float stok = s4 + __shfl_xor(s4, 16, 64);   // combine quad pairs (0,1) and (2,3)
        if((quad&1)==0){
          int tok = ((bm + wm + im*16)>>3) + (quad>>1);
          Cg[(size_t)tok*128 + col] = f2s(stok*0.125f);
        }
      } else {
        for(int r=0;r<4;r++){
          int grow = bm + wm + im*16 + quad*4 + r;
          float v = acc[im][in][r] + bv;
          if constexpr(ACT) v = v>=0.f? v : 0.01f*v;
          if constexpr(RESID) v += s2f(Rres[(size_t)grow*N + col]);
          Cg[(size_t)grow*N + col] = f2s(v);
        }
      }
    }
  }
}

// ============================= nf attention: K=8 tokens (padded LDS) =============================
__global__ __launch_bounds__(256) void nf_attn(const short* __restrict__ qkv, short* __restrict__ att){
  constexpr int QLD=392;  // 196 words; 196%32=4 -> conflict-free spread
  __shared__ short Qs[4*8*QLD];
  int t0=blockIdx.x*4, tid=threadIdx.x;
  for(int li=tid; li<1536; li+=256){
    int e=li*8;
    int tok=e/3072, rem=e-tok*3072;
    int j=rem/384, k=rem-j*384;
    *(short8*)&Qs[(tok*8+j)*QLD + k] = *(const short8*)(qkv + (size_t)t0*3072 + e);
  }
  __syncthreads();
  int lt=tid>>6, lane=tid&63;
  int h=lane>>3, q=lane&7;
  const short* base = &Qs[(lt*8)*QLD + h*16];
  float qv[16];
  for(int d=0;d<16;d++) qv[d]=s2f(base[q*QLD+d]);
  float sc[8]; float mx=-INFINITY;
  for(int j=0;j<8;j++){
    float a=0;
    for(int d=0;d<16;d++) a+=qv[d]*s2f(base[j*QLD+128+d]);
    a*=0.25f; sc[j]=a; mx=fmaxf(mx,a);
  }
  float se=0;
  for(int j=0;j<8;j++){ sc[j]=expf(sc[j]-mx); se+=sc[j]; }
  float inv=1.f/se;
  float o[16];
  for(int d=0;d<16;d++) o[d]=0.f;
  for(int j=0;j<8;j++){
    float p=sc[j];
    for(int d=0;d<16;d++) o[d]+=p*s2f(base[j*QLD+256+d]);
  }
  short* ob = att + (size_t)(t0*8 + lt*8 + q)*128 + h*16;
  for(int d=0;d<16;d++) ob[d]=f2s(o[d]*inv);
}

// ============================= rt attention: 2-way key split in-block =============================
// 512 blocks (b&255 = ray), 256 threads = 2 j-halves x (4 head-groups x 32
// lanes x 3 q-rows). Each half processes 48 keys; partials combined via LDS
// (reusing kh/vh after a barrier). Single-pass exp softmax (scores O(1)).
__global__ __launch_bounds__(256) void rt_attn(const short* __restrict__ qkvb, short* __restrict__ attout){
  int b=blockIdx.x; int i=b&255, h0=(b>>8)*4; int tid=threadIdx.x;
  __shared__ float kh[96][64], vh[96][64];   // 49152 B
  for(int idx=tid; idx<1536; idx+=256){
    int kv = idx>=768; int l = idx - kv*768;
    int j = l>>3, c = l&7;
    size_t base = ((size_t)(i*96+j))*384 + h0*16 + (kv?256:128) + c*8;
    short8 x = *(const short8*)(qkvb+base);
    float* dst = kv? &vh[j][c*8] : &kh[j][c*8];
    for(int e=0;e<8;e++) dst[e]=s2f(x[e]);
  }
  __syncthreads();
  int jh=tid>>7, t2=tid&127;
  int hh=t2>>5, lq=t2&31, h=h0+hh, r0=lq*3;
  float q[3][16];
  for(int rr=0;rr<3;rr++){
    size_t qb=((size_t)(i*96+r0+rr))*384 + h*16;
    short8 a=*(const short8*)(qkvb+qb), bq=*(const short8*)(qkvb+qb+8);
    for(int e=0;e<8;e++){ q[rr][e]=s2f(a[e]); q[rr][8+e]=s2f(bq[e]); }
  }
  float acc[3][16]; float se[3]={0.f,0.f,0.f};
  for(int rr=0;rr<3;rr++) for(int d=0;d<16;d++) acc[rr][d]=0.f;
  const float* kb=&kh[jh*48][hh*16];
  const float* vb=&vh[jh*48][hh*16];
  for(int j=0;j<48;j++){
    const float* kj = kb + j*64;
    float s0=0.f,s1=0.f,s2=0.f;
    for(int d=0;d<16;d++){ float kv_=kj[d];
      s0=fmaf(q[0][d],kv_,s0); s1=fmaf(q[1][d],kv_,s1); s2=fmaf(q[2][d],kv_,s2); }
    float p0=expf(s0*0.25f), p1=expf(s1*0.25f), p2=expf(s2*0.25f);
    se[0]+=p0; se[1]+=p1; se[2]+=p2;
    const float* vj = vb + j*64;
    for(int d=0;d<16;d++){ float vv=vj[d];
      acc[0][d]=fmaf(p0,vv,acc[0][d]); acc[1][d]=fmaf(p1,vv,acc[1][d]); acc[2][d]=fmaf(p2,vv,acc[2][d]); }
  }
  __syncthreads();   // all kh/vh reads done before reuse as partial buffer
  float* pacc=(float*)kh;  // 6144 floats, exact fit: 128 thr x 3 rows x 16
  float* pse =(float*)vh;  // 384 floats
  if(jh==1){
    for(int rr=0;rr<3;rr++){
      for(int d=0;d<16;d++) pacc[(t2*3+rr)*16+d]=acc[rr][d];
      pse[t2*3+rr]=se[rr];
    }
  }
  __syncthreads();
  if(jh==0){
    for(int rr=0;rr<3;rr++){
      float sv = se[rr] + pse[t2*3+rr];
      float inv = 1.f/sv;
      short8 o0,o1;
      for(int e=0;e<8;e++){
        float a0=acc[rr][e]   + pacc[(t2*3+rr)*16+e];
        float a1=acc[rr][8+e] + pacc[(t2*3+rr)*16+8+e];
        o0[e]=f2s(a0*inv); o1[e]=f2s(a1*inv);
      }
      size_t ob=((size_t)(i*96+r0+rr))*128 + h*16;
      *(short8*)(attout+ob)=o0;
      *(short8*)(attout+ob+8)=o1;
    }
  }
}

// ============================= radiance head =============================
__global__ __launch_bounds__(256) void k_rad(
  const short* __restrict__ h3, const float* __restrict__ fW, const float* __restrict__ fb,
  const float* __restrict__ wsf, float* __restrict__ out)
{
  int t=blockIdx.x*256+threadIdx.x;
  if(t>=NT) return;
  int i=t/S;
  float a0=fb[0], a1=fb[1], a2=fb[2];
  for(int c=0;c<C;c++){
    float hv=s2f(h3[(size_t)t*C+c]);
    a0=fmaf(hv,fW[c*3+0],a0);
    a1=fmaf(hv,fW[c*3+1],a1);
    a2=fmaf(hv,fW[c*3+2],a2);
  }
  float m=wsf[OFF_M+i];
  float r0=1.f/(1.f+expf(-a0)), r1=1.f/(1.f+expf(-a1)), r2=1.f/(1.f+expf(-a2));
  size_t ob=3*(size_t)NT+(size_t)t*3;
  out[ob+0]=m!=0.f?r0:0.f;
  out[ob+1]=m!=0.f?r1:0.f;
  out[ob+2]=m!=0.f?r2:0.f;
}

extern "C" void kernel_launch(void* const* d_in, const int* in_sizes, int n_in,
                              void* d_out, int out_size, void* d_ws, size_t ws_size,
                              hipStream_t stream) {
  (void)in_sizes; (void)n_in; (void)out_size;
  const float* rays_o =(const float*)d_in[0];
  const float* rays_d =(const float*)d_in[1];
  const float* pose   =(const float*)d_in[2];
  const float* dimv   =(const float*)d_in[3];
  const float* voxel  =(const float*)d_in[4];
  const float* fvol   =(const float*)d_in[5];
  const float* fvhr   =(const float*)d_in[6];
  const float* u_p    =(const float*)d_in[7];
  const float* u_cat  =(const float*)d_in[8];
  const float* u_lam  =(const float*)d_in[9];
  const float* dW1    =(const float*)d_in[10];
  const float* db1    =(const float*)d_in[11];
  const float* dW2    =(const float*)d_in[12];
  const float* db2    =(const float*)d_in[13];
  const float* rW0    =(const float*)d_in[14];
  const float* rb0    =(const float*)d_in[15];
  const float* nf_qkv =(const float*)d_in[16];
  const float* nf_qkvb=(const float*)d_in[17];
  const float* nf_o   =(const float*)d_in[18];
  const float* nf_ob  =(const float*)d_in[19];
  const float* nf_f1  =(const float*)d_in[20];
  const float* nf_f1b =(const float*)d_in[21];
  const float* nf_f2  =(const float*)d_in[22];
  const float* nf_f2b =(const float*)d_in[23];
  const float* rt_qkv =(const float*)d_in[24];
  const float* rt_qkvb=(const float*)d_in[25];
  const float* rt_o   =(const float*)d_in[26];
  const float* rt_ob  =(const float*)d_in[27];
  const float* rt_f1  =(const float*)d_in[28];
  const float* rt_f1b =(const float*)d_in[29];
  const float* rt_f2  =(const float*)d_in[30];
  const float* rt_f2b =(const float*)d_in[31];
  const float* fW     =(const float*)d_in[32];
  const float* fb     =(const float*)d_in[33];

  float* wsf=(float*)d_ws;
  short* wsb=(short*)((char*)d_ws + F32_CNT*4);
  float* out=(float*)d_out;

  // Chunking: smallest nch that fits ws_size (nch=1 measured fastest overall).
  int nch=8;
  for(int c=1;c<=8;c<<=1){
    size_t mc_=(size_t)MTOT/c;
    size_t region=mc_*640ULL; if(region<RT_TOT) region=RT_TOT;
    size_t need=F32_CNT*4 + 2ULL*(CHB + region);
    if(need <= ws_size){ nch=c; break; }
  }
  const size_t mc = (size_t)MTOT/nch;
  const int Tc = (int)(mc/8);

  short* WT  = wsb;
  short* H2  = wsb + H2OFF;
  short* arena = wsb + CHB;
  // nf chunk overlays: h0[0,128) qkv[128,512) att[512,640) x2[512,576)
  // x1[128,256) f1[256,512)
  short* o_h0 = arena;
  short* o_qkv= arena + (size_t)128*mc;
  short* o_x1 = arena + (size_t)128*mc;
  short* o_f1 = arena + (size_t)256*mc;
  short* o_att= arena + (size_t)512*mc;
  short* o_x2 = arena + (size_t)512*mc;
  // rt overlays: qkv[0,384) att/h3[384,512) x[0,128) f1[128,384)
  short* r_qkv= arena;
  short* r_att= arena + (size_t)384*NT;
  short* r_x  = arena;
  short* r_f1 = arena + (size_t)128*NT;
  short* r_h3 = arena + (size_t)384*NT;

  k0_setup<<<NRAY/64,64,0,stream>>>(rays_o,rays_d,pose,dimv,wsf);
  k1_sample<<<NRAY,128,0,stream>>>(rays_o,rays_d,dimv,voxel,fvol,u_p,u_cat,u_lam,wsf);
  k2_sigma<<<NT,128,0,stream>>>(dW1,db1,dW2,db2,wsf,out);
  k_wprep<<<(int)((WT_TOT+255)/256),256,0,stream>>>(rW0,nf_qkv,nf_o,nf_f1,nf_f2,rt_qkv,rt_o,rt_f1,rt_f2,WT);

  const int mt=(int)(mc/128);
  for(int ch=0; ch<nch; ++ch){
    int tok0 = ch*Tc;
    k_build<<<Tc,64,0,stream>>>(fvhr, wsf, o_x2, tok0);
    gemm_ln< 64,false,false,false><<<dim3(mt,1),256,0,stream>>>(o_x2, WT+WT_W0,  rb0,     nullptr, o_h0, 128);
    gemm_ln<128,true ,false,false><<<dim3(mt,3),256,0,stream>>>(o_h0, WT+WT_NQKV,nf_qkvb, nullptr, o_qkv,384);
    nf_attn<<<Tc/4,256,0,stream>>>(o_qkv, o_att);
    gemm_ln<128,false,false,true ><<<dim3(mt,1),256,0,stream>>>(o_att,WT+WT_NO,  nf_ob,   o_h0,    o_x1, 128);
    gemm_ln<128,true ,true ,false><<<dim3(mt,2),256,0,stream>>>(o_x1, WT+WT_NF1, nf_f1b,  nullptr, o_f1, 256);
    gemm_ln<256,false,false,true ,true><<<dim3(mt,1),256,0,stream>>>(o_f1, WT+WT_NF2, nf_f2b, o_x1,
                                                                     H2+(size_t)tok0*128, 128);
  }

  gemm_ln<128,true ,false,false><<<dim3(NT/128,3),256,0,stream>>>(H2,   WT+WT_RQKV,rt_qkvb, nullptr, r_qkv,384);
  rt_attn<<<NRAY*2,256,0,stream>>>(r_qkv, r_att);
  gemm_ln<128,false,false,true ><<<dim3(NT/128,1),256,0,stream>>>(r_att,WT+WT_RO,  rt_ob,   H2,      r_x,  128);
  gemm_ln<128,true ,true ,false><<<dim3(NT/128,2),256,0,stream>>>(r_x,  WT+WT_RF1, rt_f1b,  nullptr, r_f1, 256);
  gemm_ln<256,false,false,true ><<<dim3(NT/128,1),256,0,stream>>>(r_f1, WT+WT_RF2, rt_f2b,  r_x,     r_h3, 128);
  k_rad<<<NT/256,256,0,stream>>>(r_h3, fW, fb, wsf, out);
}

// Round 10
// 513.993 us; speedup vs baseline: 1.3896x; 1.0434x over previous
//
#include <hip/hip_runtime.h>
#include <hip/hip_bf16.h>
#include <cmath>

// Inputs/outputs float32. Geometry/sampling fp32 (k0/k1/k2). nf + rt chains as
// bf16 MFMA GEMMs (fp32 accum), LN fused into A-staging. Round 10: the two
// largest intermediates (qkv 151MB, f1 100MB) are never materialized --
// nf_qkv_attn fuses LN+qkv-GEMM+attention per 32-row tile (qkv tile in LDS),
// nf_f1f2 fuses LN+f1+lrelu+f2+resid+mean8 (f1 tile in LDS). Remaining live
// set ~150MB = L3-resident.

using bf16 = __hip_bfloat16;
#define DEV __device__ __forceinline__

typedef __attribute__((ext_vector_type(8))) short short8;
typedef __attribute__((ext_vector_type(4))) float f32x4;

DEV float s2f(short s){ unsigned u=((unsigned)(unsigned short)s)<<16; float f; __builtin_memcpy(&f,&u,4); return f; }
DEV short f2s(float f){ bf16 h=__float2bfloat16(f); short r; __builtin_memcpy(&r,&h,2); return r; }

constexpr int NRAY=256, SP=64, SI=32, S=96, KHR=8, CIN=32, C=128, NH=8, DH=16;
constexpr int NT = NRAY*S;           // 24576 tokens
constexpr int MTOT = NT*KHR;         // 196608 rows in the nf chain

// ---- fp32 ws region (element offsets) ----
constexpr size_t OFF_RI=0, OFF_TR=9, OFF_M=16, OFF_TN=272, OFF_TF=528, OFF_RDO=784,
  OFF_TS=1552, OFF_OCCS=26128, OFF_OCCT=50704, OFF_CRD=75280, OFF_XS=149008, F32_CNT=935440;

// ---- bf16 ws region (element offsets from bf16 base) ----
constexpr size_t WT_W0=0, WT_NQKV=8192, WT_NO=57344, WT_NF1=73728, WT_NF2=106496,
  WT_RQKV=139264, WT_RO=188416, WT_RF1=204800, WT_RF2=237568, WT_TOT=270336;
constexpr size_t H2OFF=WT_TOT;                 // h2: NT*128
constexpr size_t CHB=H2OFF+(size_t)NT*128;     // chunk / rt arena base
constexpr size_t RT_TOT=(size_t)NT*512;        // compacted rt arena

struct Corn { int off[8]; float wz, wy, wx; };

DEV void make_corners(float cz, float cy, float cx, Corn& Cn){
  cz=fminf(fmaxf(cz,0.f),31.f); cy=fminf(fmaxf(cy,0.f),31.f); cx=fminf(fmaxf(cx,0.f),31.f);
  int z0=(int)cz, y0=(int)cy, x0=(int)cx;
  int z1=(z0+1<31)?z0+1:31, y1=(y0+1<31)?y0+1:31, x1=(x0+1<31)?x0+1:31;
  Cn.wz=cz-(float)z0; Cn.wy=cy-(float)y0; Cn.wx=cx-(float)x0;
  int zy00=z0*1024+y0*32, zy01=z0*1024+y1*32, zy10=z1*1024+y0*32, zy11=z1*1024+y1*32;
  Cn.off[0]=zy00+x0; Cn.off[1]=zy00+x1;
  Cn.off[2]=zy01+x0; Cn.off[3]=zy01+x1;
  Cn.off[4]=zy10+x0; Cn.off[5]=zy10+x1;
  Cn.off[6]=zy11+x0; Cn.off[7]=zy11+x1;
}

DEV float interp1(const float* __restrict__ vol, const Corn& Cn){
  float v000=vol[Cn.off[0]], v001=vol[Cn.off[1]];
  float v010=vol[Cn.off[2]], v011=vol[Cn.off[3]];
  float v100=vol[Cn.off[4]], v101=vol[Cn.off[5]];
  float v110=vol[Cn.off[6]], v111=vol[Cn.off[7]];
  float wx=Cn.wx, wy=Cn.wy, wz=Cn.wz;
  float c00=v000*(1.f-wx)+v001*wx, c01=v010*(1.f-wx)+v011*wx;
  float c10=v100*(1.f-wx)+v101*wx, c11=v110*(1.f-wx)+v111*wx;
  return (c00*(1.f-wy)+c01*wy)*(1.f-wz) + (c10*(1.f-wy)+c11*wy)*wz;
}

DEV float ray_box(const float* Ri, const float* tr, const float* o3, const float* d3, const float* half){
  float tlo=-INFINITY, thi=INFINITY;
  for(int j=0;j<3;j++){
    float oo=Ri[j*3+0]*o3[0]+Ri[j*3+1]*o3[1]+Ri[j*3+2]*o3[2]+tr[j];
    float dd=Ri[j*3+0]*d3[0]+Ri[j*3+1]*d3[1]+Ri[j*3+2]*d3[2];
    if (fabsf(dd)<1e-9f) dd=1e-9f;
    float inv=1.f/dd;
    float t0=(-half[j]-oo)*inv, t1=(half[j]-oo)*inv;
    tlo=fmaxf(tlo,fminf(t0,t1)); thi=fminf(thi,fmaxf(t0,t1));
  }
  bool valid = thi >= fmaxf(tlo,0.f);
  return valid ? tlo : INFINITY;
}

// ============================= k0: pose inverse + ray-box =============================
__global__ __launch_bounds__(64) void k0_setup(
  const float* __restrict__ rays_o, const float* __restrict__ rays_d,
  const float* __restrict__ pose, const float* __restrict__ dimv,
  float* __restrict__ wsf)
{
  __shared__ float Ri[9], tr[3];
  int tid=threadIdx.x; int ray=blockIdx.x*64+tid;
  if(tid==0){
    float P[16];
    for(int j=0;j<16;j++) P[j]=pose[j];
    float a00=P[0],a01=P[1],a02=P[2],a10=P[4],a11=P[5],a12=P[6],a20=P[8],a21=P[9],a22=P[10];
    float c00=a11*a22-a12*a21, c01=a12*a20-a10*a22, c02=a10*a21-a11*a20;
    float det=a00*c00+a01*c01+a02*c02;
    float id=1.f/det;
    Ri[0]=c00*id; Ri[1]=(a02*a21-a01*a22)*id; Ri[2]=(a01*a12-a02*a11)*id;
    Ri[3]=c01*id; Ri[4]=(a00*a22-a02*a20)*id; Ri[5]=(a02*a10-a00*a12)*id;
    Ri[6]=c02*id; Ri[7]=(a01*a20-a00*a21)*id; Ri[8]=(a00*a11-a01*a10)*id;
    float t0=P[3],t1=P[7],t2=P[11];
    tr[0]=-(Ri[0]*t0+Ri[1]*t1+Ri[2]*t2);
    tr[1]=-(Ri[3]*t0+Ri[4]*t1+Ri[5]*t2);
    tr[2]=-(Ri[6]*t0+Ri[7]*t1+Ri[8]*t2);
    if(blockIdx.x==0){
      for(int j=0;j<9;j++) wsf[OFF_RI+j]=Ri[j];
      for(int j=0;j<3;j++) wsf[OFF_TR+j]=tr[j];
    }
  }
  __syncthreads();
  float o3[3],d3[3],dim[3],half[3];
  for(int j=0;j<3;j++){ o3[j]=rays_o[ray*3+j]; d3[j]=rays_d[ray*3+j];
                        dim[j]=dimv[j]; half[j]=0.5f*dim[j]; }
  float tnear=ray_box(Ri,tr,o3,d3,half);
  float tmax=tnear+10.f*(fabsf(dim[0])+fabsf(dim[1])+fabsf(dim[2]));
  float pm[3]={o3[0]+tmax*d3[0], o3[1]+tmax*d3[1], o3[2]+tmax*d3[2]};
  float nd[3]={-d3[0],-d3[1],-d3[2]};
  float tfar=tmax-ray_box(Ri,tr,pm,nd,half);
  bool mm = isfinite(tnear)&&isfinite(tfar)&&(tfar>tnear);
  wsf[OFF_M+ray]=mm?1.f:0.f;
  wsf[OFF_TN+ray]=mm?tnear:0.f;
  wsf[OFF_TF+ray]=mm?tfar:1.f;
  for(int j=0;j<3;j++)
    wsf[OFF_RDO+(size_t)ray*3+j]=Ri[j*3+0]*d3[0]+Ri[j*3+1]*d3[1]+Ri[j*3+2]*d3[2];
}

// ============================= k1: sampling + interp + stable sort =============================
__global__ __launch_bounds__(128) void k1_sample(
  const float* __restrict__ rays_o, const float* __restrict__ rays_d, const float* __restrict__ dimv,
  const float* __restrict__ voxel, const float* __restrict__ fvol,
  const float* __restrict__ u_p, const float* __restrict__ u_cat, const float* __restrict__ u_lam,
  float* __restrict__ wsf)
{
  int i=blockIdx.x, tid=threadIdx.x;
  __shared__ float Ri[9], tr[3], dim[3], o3[3], d3[3];
  __shared__ float t_all[S], occ_all[S], crd_sh[S][3];
  __shared__ int   coff[S][8];
  __shared__ float cww[S][3];
  __shared__ float cdf[SP];
  __shared__ float totv;
  __shared__ int   rnk[S];
  if(tid<9) Ri[tid]=wsf[OFF_RI+tid];
  if(tid<3){ tr[tid]=wsf[OFF_TR+tid]; dim[tid]=dimv[tid];
             o3[tid]=rays_o[i*3+tid]; d3[tid]=rays_d[i*3+tid]; }
  __syncthreads();
  float tn=wsf[OFF_TN+i], tf=wsf[OFF_TF+i];

  auto do_sample=[&](int s, float t){
    float px=o3[0]+t*d3[0], py=o3[1]+t*d3[1], pz=o3[2]+t*d3[2];
    float q0=Ri[0]*px+Ri[1]*py+Ri[2]*pz+tr[0];
    float q1=Ri[3]*px+Ri[4]*py+Ri[5]*pz+tr[1];
    float q2=Ri[6]*px+Ri[7]*py+Ri[8]*pz+tr[2];
    float cz=(0.5f+q2/dim[2])*31.f;
    float cy=(0.5f+q1/dim[1])*31.f;
    float cx=(0.5f+q0/dim[0])*31.f;
    crd_sh[s][0]=cz; crd_sh[s][1]=cy; crd_sh[s][2]=cx;
    Corn Cn; make_corners(cz,cy,cx,Cn);
    for(int q=0;q<8;q++) coff[s][q]=Cn.off[q];
    cww[s][0]=Cn.wz; cww[s][1]=Cn.wy; cww[s][2]=Cn.wx;
    occ_all[s]=interp1(voxel,Cn);
    t_all[s]=t;
  };

  if(tid<SP){
    float u=u_p[i*SP+tid];
    float t=tn+(tf-tn)*((float)tid+u)*(1.f/64.f);
    do_sample(tid,t);
  }
  __syncthreads();
  if(tid==0){
    float c=0;
    for(int j=0;j<SP-1;j++){ float pr=occ_all[j]+occ_all[j+1]; pr=fmaxf(pr,1e-12f); c+=pr; cdf[j]=c; }
    totv=c;
  }
  __syncthreads();
  if(tid<SP-1) cdf[tid]=cdf[tid]/totv;
  __syncthreads();
  if(tid<SI){
    float u=u_cat[i*SI+tid];
    int cnt=0;
    for(int j=0;j<SP-1;j++) cnt += (u>=cdf[j])?1:0;
    int ind=(cnt<SP-2)?cnt:(SP-2);
    float lam=u_lam[i*SI+tid];
    float tfine=lam*t_all[ind]+(1.f-lam)*t_all[ind+1];
    do_sample(SP+tid,tfine);
  }
  __syncthreads();
  if(tid<S){  // stable counting-rank sort (== stable argsort)
    float ts=t_all[tid]; int r=0;
    for(int j=0;j<S;j++){ float tj=t_all[j]; r += (tj<ts || (tj==ts && j<tid)) ? 1:0; }
    rnk[tid]=r;
    size_t base=(size_t)i*S+r;
    wsf[OFF_TS+base]=ts;
    wsf[OFF_OCCS+base]=occ_all[tid];
    wsf[OFF_CRD+base*3+0]=crd_sh[tid][0];
    wsf[OFF_CRD+base*3+1]=crd_sh[tid][1];
    wsf[OFF_CRD+base*3+2]=crd_sh[tid][2];
  }
  __syncthreads();
  for(int idx=tid; idx<S*CIN; idx+=128){
    int s=idx>>5, c=idx&31;
    float wz=cww[s][0], wy=cww[s][1], wx=cww[s][2];
    const float* vc=fvol+(size_t)c*32768;
    float v000=vc[coff[s][0]], v001=vc[coff[s][1]];
    float v010=vc[coff[s][2]], v011=vc[coff[s][3]];
    float v100=vc[coff[s][4]], v101=vc[coff[s][5]];
    float v110=vc[coff[s][6]], v111=vc[coff[s][7]];
    float c00=v000*(1.f-wx)+v001*wx, c01=v010*(1.f-wx)+v011*wx;
    float c10=v100*(1.f-wx)+v101*wx, c11=v110*(1.f-wx)+v111*wx;
    float val=(c00*(1.f-wy)+c01*wy)*(1.f-wz)+(c10*(1.f-wy)+c11*wy)*wz;
    wsf[OFF_XS+((size_t)i*S+rnk[s])*CIN+c]=val;
  }
}

// ============================= k2: sigma MLP, alpha, outputs 0..2 =============================
__global__ __launch_bounds__(128) void k2_sigma(
  const float* __restrict__ dW1, const float* __restrict__ db1,
  const float* __restrict__ dW2, const float* __restrict__ db2,
  float* __restrict__ wsf, float* __restrict__ out)
{
  int t=blockIdx.x, tid=threadIdx.x, i=t/S;
  __shared__ float xx[33];
  __shared__ float part[2];
  if(tid<32) xx[tid]=wsf[OFF_XS+(size_t)t*32+tid];
  if(tid==32) xx[32]=wsf[OFF_OCCS+t];
  __syncthreads();
  float acc=db1[tid];
  for(int k=0;k<33;k++) acc=fmaf(xx[k], dW1[k*C+tid], acc);
  acc = acc>=0.f?acc:0.01f*acc;
  float g = acc*dW2[tid];
  for(int off=32;off;off>>=1) g+=__shfl_down(g,off,64);
  if((tid&63)==0) part[tid>>6]=g;
  __syncthreads();
  if(tid==0){
    float z=part[0]+part[1]+db2[0];
    float sg=1.f/(1.f+expf(-z));
    float occ=xx[32];
    float occt=occ<0.7f?0.f:occ;
    float alpha=occt*sg;
    float m=wsf[OFF_M+i];
    float ts=wsf[OFF_TS+t];
    out[t]      =m!=0.f?ts:0.f;
    out[NT+t]   =m!=0.f?alpha:0.f;
    out[2*NT+t] =m!=0.f?occt:0.f;
    wsf[OFF_OCCT+t]=occt;
  }
}

// ============================= weight prep: fp32 KxN -> bf16 N x Kpad (B^T) =============================
__global__ __launch_bounds__(256) void k_wprep(
  const float* __restrict__ w0, const float* __restrict__ nqkv, const float* __restrict__ no_,
  const float* __restrict__ nf1, const float* __restrict__ nf2,
  const float* __restrict__ rqkv, const float* __restrict__ ro_,
  const float* __restrict__ rf1, const float* __restrict__ rf2,
  short* __restrict__ WT)
{
  int gid = blockIdx.x*256+threadIdx.x;
  if(gid>=(int)WT_TOT) return;
  const float* src; int K,N,Kp; int base;
  if(gid<8192){src=w0;K=42;N=128;Kp=64;base=0;}
  else if(gid<57344){src=nqkv;K=128;N=384;Kp=128;base=8192;}
  else if(gid<73728){src=no_;K=128;N=128;Kp=128;base=57344;}
  else if(gid<106496){src=nf1;K=128;N=256;Kp=128;base=73728;}
  else if(gid<139264){src=nf2;K=256;N=128;Kp=256;base=106496;}
  else if(gid<188416){src=rqkv;K=128;N=384;Kp=128;base=139264;}
  else if(gid<204800){src=ro_;K=128;N=128;Kp=128;base=188416;}
  else if(gid<237568){src=rf1;K=128;N=256;Kp=128;base=204800;}
  else {src=rf2;K=256;N=128;Kp=256;base=237568;}
  int local=gid-base; int n=local/Kp, k=local%Kp;
  WT[gid] = (k<K)? f2s(src[(size_t)k*N+n]) : (short)0;
}

// ============================= xx2 builder: X2 (rows x 64 bf16, cols42..63=0) =============================
__global__ __launch_bounds__(64) void k_build(
  const float* __restrict__ fvhr, const float* __restrict__ wsf,
  short* __restrict__ X2, int tok0)
{
  int tloc=blockIdx.x, tid=threadIdx.x;
  int t=tok0+tloc, i=t/S;
  __shared__ float hr[KHR][6];
  __shared__ float xf[32];
  __shared__ float RiS[9];
  __shared__ float geo[4];
  __shared__ float crd[3];
  if(tid<9) RiS[tid]=wsf[OFF_RI+tid];
  if(tid>=16&&tid<19) crd[tid-16]=wsf[OFF_CRD+(size_t)t*3+(tid-16)];
  if(tid>=32) xf[tid-32]=wsf[OFF_XS+(size_t)t*32+(tid-32)];
  if(tid==9) geo[0]=wsf[OFF_OCCT+t];
  if(tid>=12&&tid<15) geo[1+(tid-12)]=wsf[OFF_RDO+(size_t)i*3+(tid-12)];
  __syncthreads();
  if(tid<48){
    int k=tid/6, ch=tid%6;
    Corn Cn; make_corners(crd[0],crd[1],crd[2],Cn);
    hr[k][ch]=interp1(fvhr+(size_t)(k*6+ch)*32768, Cn);
  }
  __syncthreads();
  for(int idx=tid; idx<512; idx+=64){
    int k=idx>>6, j=idx&63; float v;
    if(j<32) v=xf[j];
    else if(j<35) v=hr[k][j-32];
    else if(j<38){int r=j-35; v=hr[k][3]*RiS[r*3+0]+hr[k][4]*RiS[r*3+1]+hr[k][5]*RiS[r*3+2];}
    else if(j<41) v=geo[1+(j-38)];
    else if(j==41) v=geo[0];
    else v=0.f;
    X2[(size_t)(tloc*8+k)*64 + j]=f2s(v);
  }
}

// ============================= MFMA GEMM: C = [LN?](A) @ Bt^T + bias [+lrelu] [+resid] =============================
// Grid: x = M-tiles, y = N-tiles (round-6 measured-best order).
template<int K, bool LNA, bool ACT, bool RESID>
__global__ __launch_bounds__(256) void gemm_ln(
  const short* __restrict__ A, const short* __restrict__ Bt,
  const float* __restrict__ bias, const short* __restrict__ Rres,
  short* __restrict__ Cg, int N)
{
  static_assert(!LNA || K==128, "LNA requires K==128");
  constexpr int KSA = (K<128)?K:128;
  constexpr int NSA = K/KSA;
  constexpr int LDA = KSA+8;
  constexpr int LDB = 64+8;
  __shared__ short Al[128*LDA];
  __shared__ short Bl[128*LDB];
  const int tid=threadIdx.x;
  const int bm=blockIdx.x*128, bn=blockIdx.y*128;
  const int lane=tid&63, wave=tid>>6;
  const int wm=(wave>>1)*64, wn=(wave&1)*64;
  const int quad=lane>>4, m16=lane&15;
  f32x4 acc[4][4];
  for(int a=0;a<4;a++) for(int b=0;b<4;b++) acc[a][b]=(f32x4){0.f,0.f,0.f,0.f};

  for(int sa=0; sa<NSA; ++sa){
    if(sa>0) __syncthreads();
    constexpr int CH8=KSA/8;
    for(int it=0; it<(128*CH8)/256; ++it){
      int li=it*256+tid; int row=li/CH8, kc=li%CH8;
      short8 v = *(const short8*)(A + (size_t)(bm+row)*K + sa*KSA + kc*8);
      if constexpr(LNA){
        float f[8]; float ls=0.f,lq=0.f;
        for(int e=0;e<8;e++){ f[e]=s2f(v[e]); ls+=f[e]; lq+=f[e]*f[e]; }
        for(int off=8;off;off>>=1){ ls+=__shfl_xor(ls,off,16); lq+=__shfl_xor(lq,off,16); }
        float mu=ls*(1.f/128.f);
        float var=lq*(1.f/128.f)-mu*mu;
        float rs=rsqrtf(var+1e-5f);
        for(int e=0;e<8;e++) v[e]=f2s((f[e]-mu)*rs);
      }
      *(short8*)&Al[row*LDA+kc*8]=v;
    }
    __syncthreads();
    for(int sb=0; sb<KSA/64; ++sb){
      if(sb>0) __syncthreads();
      for(int it=0; it<4; ++it){
        int li=it*256+tid; int row=li>>3, kc=li&7;
        *(short8*)&Bl[row*LDB+kc*8] =
          *(const short8*)(Bt + (size_t)(bn+row)*K + sa*KSA + sb*64 + kc*8);
      }
      __syncthreads();
      for(int kk=0; kk<64; kk+=32){
        int ka = sb*64+kk;
        short8 af[4], bfv[4];
        for(int im=0; im<4; im++)
          af[im] = *(const short8*)&Al[(wm+im*16+m16)*LDA + ka + quad*8];
        for(int in=0; in<4; in++)
          bfv[in] = *(const short8*)&Bl[(wn+in*16+m16)*LDB + kk + quad*8];
        for(int im=0;im<4;im++)
          for(int in=0;in<4;in++)
            acc[im][in] = __builtin_amdgcn_mfma_f32_16x16x32_bf16(af[im], bfv[in], acc[im][in], 0,0,0);
      }
    }
  }
  for(int in=0;in<4;in++){
    int col = bn + wn + in*16 + m16;
    float bv = bias[col];
    for(int im=0;im<4;im++){
      for(int r=0;r<4;r++){
        int grow = bm + wm + im*16 + quad*4 + r;
        float v = acc[im][in][r] + bv;
        if constexpr(ACT) v = v>=0.f? v : 0.01f*v;
        if constexpr(RESID) v += s2f(Rres[(size_t)grow*N + col]);
        Cg[(size_t)grow*N + col] = f2s(v);
      }
    }
  }
}

// ============================= fused nf: LN -> qkv GEMM (in LDS) -> attention -> att =========
// 32 rows (4 tokens) per block. qkv tile never leaves LDS (saves 302 MB HBM).
// LDS: Al 8704 + Bl 30720 + Qt 25088 = 64512 B.
__global__ __launch_bounds__(256) void nf_qkv_attn(
  const short* __restrict__ A, const short* __restrict__ Bt,
  const float* __restrict__ bias, short* __restrict__ att)
{
  __shared__ short Al[32*136];
  __shared__ short Bl[384*40];
  __shared__ short Qt[32*392];
  const int tid=threadIdx.x;
  const int bm=blockIdx.x*32;
  // stage A (32x128) with LN
  for(int it=0; it<2; ++it){
    int li=it*256+tid; int row=li>>4, kc=li&15;
    short8 v = *(const short8*)(A + (size_t)(bm+row)*128 + kc*8);
    float f[8]; float ls=0.f,lq=0.f;
    for(int e=0;e<8;e++){ f[e]=s2f(v[e]); ls+=f[e]; lq+=f[e]*f[e]; }
    for(int off=8;off;off>>=1){ ls+=__shfl_xor(ls,off,16); lq+=__shfl_xor(lq,off,16); }
    float mu=ls*(1.f/128.f);
    float var=lq*(1.f/128.f)-mu*mu;
    float rs=rsqrtf(var+1e-5f);
    for(int e=0;e<8;e++) v[e]=f2s((f[e]-mu)*rs);
    *(short8*)&Al[row*136+kc*8]=v;
  }
  const int lane=tid&63, wave=tid>>6;
  const int quad=lane>>4, m16=lane&15;
  const int wn=wave*96;
  f32x4 acc[2][6];
  for(int a=0;a<2;a++) for(int b=0;b<6;b++) acc[a][b]=(f32x4){0.f,0.f,0.f,0.f};
  for(int kc2=0;kc2<4;++kc2){
    __syncthreads();
    for(int it=0; it<6; ++it){
      int li=it*256+tid; int row=li>>2, c=li&3;
      *(short8*)&Bl[row*40+c*8] = *(const short8*)(Bt + (size_t)row*128 + kc2*32 + c*8);
    }
    __syncthreads();
    int ka=kc2*32;
    short8 af[2], bfv[6];
    af[0]=*(const short8*)&Al[m16*136 + ka + quad*8];
    af[1]=*(const short8*)&Al[(16+m16)*136 + ka + quad*8];
    for(int in=0;in<6;in++) bfv[in]=*(const short8*)&Bl[(wn+in*16+m16)*40 + quad*8];
    for(int im=0;im<2;im++)
      for(int in=0;in<6;in++)
        acc[im][in]=__builtin_amdgcn_mfma_f32_16x16x32_bf16(af[im],bfv[in],acc[im][in],0,0,0);
  }
  // write qkv tile (+bias) into LDS
  for(int in=0;in<6;in++){
    int col=wn+in*16+m16;
    float bv=bias[col];
    for(int im=0;im<2;im++)
      for(int r=0;r<4;r++)
        Qt[(im*16+quad*4+r)*392+col]=f2s(acc[im][in][r]+bv);
  }
  __syncthreads();
  // attention: 256 threads = 4 tok x 8 head x 8 q
  int tok=tid>>6, h=(tid>>3)&7, q=tid&7;
  const short* base=&Qt[(tok*8)*392 + h*16];
  float qv[16];
  for(int d=0;d<16;d++) qv[d]=s2f(base[q*392+d]);
  float sc[8]; float mx=-INFINITY;
  for(int j=0;j<8;j++){
    float a=0;
    for(int d=0;d<16;d++) a+=qv[d]*s2f(base[j*392+128+d]);
    a*=0.25f; sc[j]=a; mx=fmaxf(mx,a);
  }
  float se=0;
  for(int j=0;j<8;j++){ sc[j]=expf(sc[j]-mx); se+=sc[j]; }
  float inv=1.f/se;
  float o[16];
  for(int d=0;d<16;d++) o[d]=0.f;
  for(int j=0;j<8;j++){
    float p=sc[j];
    for(int d=0;d<16;d++) o[d]+=p*s2f(base[j*392+256+d]);
  }
  short8 o0,o1;
  for(int e=0;e<8;e++){ o0[e]=f2s(o[e]*inv); o1[e]=f2s(o[8+e]*inv); }
  size_t ob=(size_t)(bm+tok*8+q)*128 + h*16;
  *(short8*)(att+ob)=o0;
  *(short8*)(att+ob+8)=o1;
}

// ============================= fused nf: LN -> f1 (lrelu, LDS) -> f2 (+resid, mean8) -> H2 ====
// 32 rows per block. f1 tile never leaves LDS (saves 200 MB HBM).
// LDS: Al 8704 + Bl 20480 + F1 16896 = 46080 B.
__global__ __launch_bounds__(256) void nf_f1f2(
  const short* __restrict__ X1, const short* __restrict__ Bt1, const float* __restrict__ b1,
  const short* __restrict__ Bt2, const float* __restrict__ b2,
  short* __restrict__ H2)
{
  __shared__ short Al[32*136];
  __shared__ short Bl[256*40];
  __shared__ short F1[32*264];
  const int tid=threadIdx.x;
  const int bm=blockIdx.x*32;
  for(int it=0; it<2; ++it){
    int li=it*256+tid; int row=li>>4, kc=li&15;
    short8 v = *(const short8*)(X1 + (size_t)(bm+row)*128 + kc*8);
    float f[8]; float ls=0.f,lq=0.f;
    for(int e=0;e<8;e++){ f[e]=s2f(v[e]); ls+=f[e]; lq+=f[e]*f[e]; }
    for(int off=8;off;off>>=1){ ls+=__shfl_xor(ls,off,16); lq+=__shfl_xor(lq,off,16); }
    float mu=ls*(1.f/128.f);
    float var=lq*(1.f/128.f)-mu*mu;
    float rs=rsqrtf(var+1e-5f);
    for(int e=0;e<8;e++) v[e]=f2s((f[e]-mu)*rs);
    *(short8*)&Al[row*136+kc*8]=v;
  }
  const int lane=tid&63, wave=tid>>6;
  const int quad=lane>>4, m16=lane&15;
  // ---- f1: N=256, wave strip 64 ----
  {
    const int wn=wave*64;
    f32x4 acc[2][4];
    for(int a=0;a<2;a++) for(int b=0;b<4;b++) acc[a][b]=(f32x4){0.f,0.f,0.f,0.f};
    for(int kc2=0;kc2<4;++kc2){
      __syncthreads();
      for(int it=0; it<4; ++it){
        int li=it*256+tid; int row=li>>2, c=li&3;
        *(short8*)&Bl[row*40+c*8] = *(const short8*)(Bt1 + (size_t)row*128 + kc2*32 + c*8);
      }
      __syncthreads();
      int ka=kc2*32;
      short8 af[2], bfv[4];
      af[0]=*(const short8*)&Al[m16*136 + ka + quad*8];
      af[1]=*(const short8*)&Al[(16+m16)*136 + ka + quad*8];
      for(int in=0;in<4;in++) bfv[in]=*(const short8*)&Bl[(wn+in*16+m16)*40 + quad*8];
      for(int im=0;im<2;im++)
        for(int in=0;in<4;in++)
          acc[im][in]=__builtin_amdgcn_mfma_f32_16x16x32_bf16(af[im],bfv[in],acc[im][in],0,0,0);
    }
    for(int in=0;in<4;in++){
      int col=wn+in*16+m16;
      float bv=b1[col];
      for(int im=0;im<2;im++)
        for(int r=0;r<4;r++){
          float v=acc[im][in][r]+bv;
          v = v>=0.f? v : 0.01f*v;
          F1[(im*16+quad*4+r)*264+col]=f2s(v);
        }
    }
  }
  __syncthreads();
  // ---- f2: K=256 from F1, N=128, wave strip 32, +resid, mean8 -> H2 ----
  {
    const int wn=wave*32;
    f32x4 acc[2][2];
    for(int a=0;a<2;a++) for(int b=0;b<2;b++) acc[a][b]=(f32x4){0.f,0.f,0.f,0.f};
    for(int kc2=0;kc2<8;++kc2){
      __syncthreads();
      for(int it=0; it<2; ++it){
        int li=it*256+tid; int row=li>>2, c=li&3;
        *(short8*)&Bl[row*40+c*8] = *(const short8*)(Bt2 + (size_t)row*256 + kc2*32 + c*8);
      }
      __syncthreads();
      int ka=kc2*32;
      short8 af[2], bfv[2];
      af[0]=*(const short8*)&F1[m16*264 + ka + quad*8];
      af[1]=*(const short8*)&F1[(16+m16)*264 + ka + quad*8];
      for(int in=0;in<2;in++) bfv[in]=*(const short8*)&Bl[(wn+in*16+m16)*40 + quad*8];
      for(int im=0;im<2;im++)
        for(int in=0;in<2;in++)
          acc[im][in]=__builtin_amdgcn_mfma_f32_16x16x32_bf16(af[im],bfv[in],acc[im][in],0,0,0);
    }
    for(int in=0;in<2;in++){
      int col=wn+in*16+m16;
      float bv=b2[col];
      for(int im=0;im<2;im++){
        float s4=0.f;
        for(int r=0;r<4;r++){
          int grow=bm+im*16+quad*4+r;
          float v=acc[im][in][r]+bv + s2f(X1[(size_t)grow*128+col]);
          s4+=v;
        }
        float stok = s4 + __shfl_xor(s4,16,64);
        if((quad&1)==0){
          int tok=((bm+im*16)>>3)+(quad>>1);
          H2[(size_t)tok*128+col]=f2s(stok*0.125f);
        }
      }
    }
  }
}

// ============================= rt attention: 2-way key split in-block =============================
__global__ __launch_bounds__(256) void rt_attn(const short* __restrict__ qkvb, short* __restrict__ attout){
  int b=blockIdx.x; int i=b&255, h0=(b>>8)*4; int tid=threadIdx.x;
  __shared__ float kh[96][64], vh[96][64];   // 49152 B
  for(int idx=tid; idx<1536; idx+=256){
    int kv = idx>=768; int l = idx - kv*768;
    int j = l>>3, c = l&7;
    size_t base = ((size_t)(i*96+j))*384 + h0*16 + (kv?256:128) + c*8;
    short8 x = *(const short8*)(qkvb+base);
    float* dst = kv? &vh[j][c*8] : &kh[j][c*8];
    for(int e=0;e<8;e++) dst[e]=s2f(x[e]);
  }
  __syncthreads();
  int jh=tid>>7, t2=tid&127;
  int hh=t2>>5, lq=t2&31, h=h0+hh, r0=lq*3;
  float q[3][16];
  for(int rr=0;rr<3;rr++){
    size_t qb=((size_t)(i*96+r0+rr))*384 + h*16;
    short8 a=*(const short8*)(qkvb+qb), bq=*(const short8*)(qkvb+qb+8);
    for(int e=0;e<8;e++){ q[rr][e]=s2f(a[e]); q[rr][8+e]=s2f(bq[e]); }
  }
  float acc[3][16]; float se[3]={0.f,0.f,0.f};
  for(int rr=0;rr<3;rr++) for(int d=0;d<16;d++) acc[rr][d]=0.f;
  const float* kb=&kh[jh*48][hh*16];
  const float* vb=&vh[jh*48][hh*16];
  for(int j=0;j<48;j++){
    const float* kj = kb + j*64;
    float s0=0.f,s1=0.f,s2=0.f;
    for(int d=0;d<16;d++){ float kv_=kj[d];
      s0=fmaf(q[0][d],kv_,s0); s1=fmaf(q[1][d],kv_,s1); s2=fmaf(q[2][d],kv_,s2); }
    float p0=expf(s0*0.25f), p1=expf(s1*0.25f), p2=expf(s2*0.25f);
    se[0]+=p0; se[1]+=p1; se[2]+=p2;
    const float* vj = vb + j*64;
    for(int d=0;d<16;d++){ float vv=vj[d];
      acc[0][d]=fmaf(p0,vv,acc[0][d]); acc[1][d]=fmaf(p1,vv,acc[1][d]); acc[2][d]=fmaf(p2,vv,acc[2][d]); }
  }
  __syncthreads();
  float* pacc=(float*)kh;
  float* pse =(float*)vh;
  if(jh==1){
    for(int rr=0;rr<3;rr++){
      for(int d=0;d<16;d++) pacc[(t2*3+rr)*16+d]=acc[rr][d];
      pse[t2*3+rr]=se[rr];
    }
  }
  __syncthreads();
  if(jh==0){
    for(int rr=0;rr<3;rr++){
      float sv = se[rr] + pse[t2*3+rr];
      float inv = 1.f/sv;
      short8 o0,o1;
      for(int e=0;e<8;e++){
        float a0=acc[rr][e]   + pacc[(t2*3+rr)*16+e];
        float a1=acc[rr][8+e] + pacc[(t2*3+rr)*16+8+e];
        o0[e]=f2s(a0*inv); o1[e]=f2s(a1*inv);
      }
      size_t ob=((size_t)(i*96+r0+rr))*128 + h*16;
      *(short8*)(attout+ob)=o0;
      *(short8*)(attout+ob+8)=o1;
    }
  }
}

// ============================= radiance head =============================
__global__ __launch_bounds__(256) void k_rad(
  const short* __restrict__ h3, const float* __restrict__ fW, const float* __restrict__ fb,
  const float* __restrict__ wsf, float* __restrict__ out)
{
  int t=blockIdx.x*256+threadIdx.x;
  if(t>=NT) return;
  int i=t/S;
  float a0=fb[0], a1=fb[1], a2=fb[2];
  for(int c=0;c<C;c++){
    float hv=s2f(h3[(size_t)t*C+c]);
    a0=fmaf(hv,fW[c*3+0],a0);
    a1=fmaf(hv,fW[c*3+1],a1);
    a2=fmaf(hv,fW[c*3+2],a2);
  }
  float m=wsf[OFF_M+i];
  float r0=1.f/(1.f+expf(-a0)), r1=1.f/(1.f+expf(-a1)), r2=1.f/(1.f+expf(-a2));
  size_t ob=3*(size_t)NT+(size_t)t*3;
  out[ob+0]=m!=0.f?r0:0.f;
  out[ob+1]=m!=0.f?r1:0.f;
  out[ob+2]=m!=0.f?r2:0.f;
}

extern "C" void kernel_launch(void* const* d_in, const int* in_sizes, int n_in,
                              void* d_out, int out_size, void* d_ws, size_t ws_size,
                              hipStream_t stream) {
  (void)in_sizes; (void)n_in; (void)out_size;
  const float* rays_o =(const float*)d_in[0];
  const float* rays_d =(const float*)d_in[1];
  const float* pose   =(const float*)d_in[2];
  const float* dimv   =(const float*)d_in[3];
  const float* voxel  =(const float*)d_in[4];
  const float* fvol   =(const float*)d_in[5];
  const float* fvhr   =(const float*)d_in[6];
  const float* u_p    =(const float*)d_in[7];
  const float* u_cat  =(const float*)d_in[8];
  const float* u_lam  =(const float*)d_in[9];
  const float* dW1    =(const float*)d_in[10];
  const float* db1    =(const float*)d_in[11];
  const float* dW2    =(const float*)d_in[12];
  const float* db2    =(const float*)d_in[13];
  const float* rW0    =(const float*)d_in[14];
  const float* rb0    =(const float*)d_in[15];
  const float* nf_qkv =(const float*)d_in[16];
  const float* nf_qkvb=(const float*)d_in[17];
  const float* nf_o   =(const float*)d_in[18];
  const float* nf_ob  =(const float*)d_in[19];
  const float* nf_f1  =(const float*)d_in[20];
  const float* nf_f1b =(const float*)d_in[21];
  const float* nf_f2  =(const float*)d_in[22];
  const float* nf_f2b =(const float*)d_in[23];
  const float* rt_qkv =(const float*)d_in[24];
  const float* rt_qkvb=(const float*)d_in[25];
  const float* rt_o   =(const float*)d_in[26];
  const float* rt_ob  =(const float*)d_in[27];
  const float* rt_f1  =(const float*)d_in[28];
  const float* rt_f1b =(const float*)d_in[29];
  const float* rt_f2  =(const float*)d_in[30];
  const float* rt_f2b =(const float*)d_in[31];
  const float* fW     =(const float*)d_in[32];
  const float* fb     =(const float*)d_in[33];

  float* wsf=(float*)d_ws;
  short* wsb=(short*)((char*)d_ws + F32_CNT*4);
  float* out=(float*)d_out;

  // Chunking: smallest nch that fits ws_size (nch=1 measured fastest overall).
  int nch=8;
  for(int c=1;c<=8;c<<=1){
    size_t mc_=(size_t)MTOT/c;
    size_t region=mc_*640ULL; if(region<RT_TOT) region=RT_TOT;
    size_t need=F32_CNT*4 + 2ULL*(CHB + region);
    if(need <= ws_size){ nch=c; break; }
  }
  const size_t mc = (size_t)MTOT/nch;
  const int Tc = (int)(mc/8);

  short* WT  = wsb;
  short* H2  = wsb + H2OFF;
  short* arena = wsb + CHB;
  // nf chunk overlays: h0[0,128) x1[128,256) att[512,640) x2[512,576)
  short* o_h0 = arena;
  short* o_x1 = arena + (size_t)128*mc;
  short* o_att= arena + (size_t)512*mc;
  short* o_x2 = arena + (size_t)512*mc;
  // rt overlays: qkv[0,384) att/h3[384,512) x[0,128) f1[128,384)
  short* r_qkv= arena;
  short* r_att= arena + (size_t)384*NT;
  short* r_x  = arena;
  short* r_f1 = arena + (size_t)128*NT;
  short* r_h3 = arena + (size_t)384*NT;

  k0_setup<<<NRAY/64,64,0,stream>>>(rays_o,rays_d,pose,dimv,wsf);
  k1_sample<<<NRAY,128,0,stream>>>(rays_o,rays_d,dimv,voxel,fvol,u_p,u_cat,u_lam,wsf);
  k2_sigma<<<NT,128,0,stream>>>(dW1,db1,dW2,db2,wsf,out);
  k_wprep<<<(int)((WT_TOT+255)/256),256,0,stream>>>(rW0,nf_qkv,nf_o,nf_f1,nf_f2,rt_qkv,rt_o,rt_f1,rt_f2,WT);

  const int mt=(int)(mc/128);
  const int mt32=(int)(mc/32);
  for(int ch=0; ch<nch; ++ch){
    int tok0 = ch*Tc;
    k_build<<<Tc,64,0,stream>>>(fvhr, wsf, o_x2, tok0);
    gemm_ln< 64,false,false,false><<<dim3(mt,1),256,0,stream>>>(o_x2, WT+WT_W0,  rb0,     nullptr, o_h0, 128);
    nf_qkv_attn<<<mt32,256,0,stream>>>(o_h0, WT+WT_NQKV, nf_qkvb, o_att);
    gemm_ln<128,false,false,true ><<<dim3(mt,1),256,0,stream>>>(o_att,WT+WT_NO,  nf_ob,   o_h0,    o_x1, 128);
    nf_f1f2<<<mt32,256,0,stream>>>(o_x1, WT+WT_NF1, nf_f1b, WT+WT_NF2, nf_f2b,
                                   H2+(size_t)tok0*128);
  }

  gemm_ln<128,true ,false,false><<<dim3(NT/128,3),256,0,stream>>>(H2,   WT+WT_RQKV,rt_qkvb, nullptr, r_qkv,384);
  rt_attn<<<NRAY*2,256,0,stream>>>(r_qkv, r_att);
  gemm_ln<128,false,false,true ><<<dim3(NT/128,1),256,0,stream>>>(r_att,WT+WT_RO,  rt_ob,   H2,      r_x,  128);
  gemm_ln<128,true ,true ,false><<<dim3(NT/128,2),256,0,stream>>>(r_x,  WT+WT_RF1, rt_f1b,  nullptr, r_f1, 256);
  gemm_ln<256,false,false,true ><<<dim3(NT/128,1),256,0,stream>>>(r_f1, WT+WT_RF2, rt_f2b,  r_x,     r_h3, 128);
  k_rad<<<NT/256,256,0,stream>>>(r_h3, fW, fb, wsf, out);
}